// Round 3
// baseline (972.945 us; speedup 1.0000x reference)
//
#include <hip/hip_runtime.h>
#include <hip/hip_bf16.h>

typedef __hip_bfloat16 bf16;
__device__ __forceinline__ float tofb(bf16 v) { return __bfloat162float(v); }
__device__ __forceinline__ bf16 tob(float v) { return __float2bfloat16(v); }

#define SCAN_T 1024

// ---------------- edge-layout probe: int32 (stride 1) vs raw int64 (stride 2) ----------------
__global__ void detect_kernel(const int* __restrict__ e, int* __restrict__ flag) {
    if (threadIdx.x == 0 && blockIdx.x == 0) {
        int s = 0;
        for (int k = 1; k < 64; k += 2) s |= e[k];
        // raw int64 little-endian: odd int32 slots are high words == 0 (values < 2^31)
        flag[0] = (s == 0) ? 2 : 1;
    }
}

// ---------------- CSR construction ----------------

__global__ __launch_bounds__(256) void count_kernel(const int* __restrict__ eidx,
                                                    const int* __restrict__ flag,
                                                    int* __restrict__ cnt, int E, int n) {
    int stride = flag[0];
    int e = blockIdx.x * 256 + threadIdx.x;
    if (e < E) {
        int d = eidx[(size_t)E * stride + (size_t)e * stride];  // dst row
        if ((unsigned)d < (unsigned)n) atomicAdd(&cnt[d], 1);
    }
}

// single-block exclusive prefix sum over cnt[0..n) -> offs[0..n], plus dinv = rsqrt(deg+1)
__global__ __launch_bounds__(SCAN_T) void scan_kernel(const int* __restrict__ cnt,
                                                      int* __restrict__ offs,
                                                      float* __restrict__ dinv, int n) {
    __shared__ int s[SCAN_T];
    __shared__ int carry_s;
    if (threadIdx.x == 0) carry_s = 0;
    __syncthreads();
    int nchunk = (n + SCAN_T - 1) / SCAN_T;
    for (int ch = 0; ch < nchunk; ++ch) {
        int i = ch * SCAN_T + threadIdx.x;
        int v = (i < n) ? cnt[i] : 0;
        if (i < n) dinv[i] = rsqrtf((float)v + 1.0f);  // +1 self-loop
        s[threadIdx.x] = v;
        __syncthreads();
        for (int off = 1; off < SCAN_T; off <<= 1) {
            int t = (threadIdx.x >= off) ? s[threadIdx.x - off] : 0;
            __syncthreads();
            s[threadIdx.x] += t;
            __syncthreads();
        }
        int carry = carry_s;
        if (i < n) offs[i] = carry + s[threadIdx.x] - v;  // exclusive
        __syncthreads();
        if (threadIdx.x == SCAN_T - 1) {
            carry_s = carry + s[SCAN_T - 1];
            if (ch == nchunk - 1) offs[n] = carry_s;
        }
        __syncthreads();
    }
}

__global__ __launch_bounds__(256) void scatter_kernel(const int* __restrict__ eidx,
                                                      const int* __restrict__ flag,
                                                      const int* __restrict__ offs,
                                                      int* __restrict__ cursor,
                                                      int* __restrict__ csr, int E, int n) {
    int stride = flag[0];
    int e = blockIdx.x * 256 + threadIdx.x;
    if (e < E) {
        int d = eidx[(size_t)E * stride + (size_t)e * stride];
        int srcv = eidx[(size_t)e * stride];
        if ((unsigned)d < (unsigned)n && (unsigned)srcv < (unsigned)n) {
            int pos = atomicAdd(&cursor[d], 1);
            csr[offs[d] + pos] = srcv;
        }
    }
}

// ---------------- dense pre-pass: hs1 = dinv * (x @ conv1_w), gg branch ----------------

__global__ __launch_bounds__(128) void pre_kernel(
    const float* __restrict__ x, const float* __restrict__ conv1_w,
    const float* __restrict__ ln1_w, const float* __restrict__ ln1_b,
    const float* __restrict__ ln2_w, const float* __restrict__ ln2_b,
    const float* __restrict__ dinv,
    bf16* __restrict__ hs1, float* __restrict__ gg, int n) {
    int i = blockIdx.x;
    if (i >= n) return;
    int c = threadIdx.x;
    __shared__ float xs[16];
    __shared__ float t1[32];
    if (c < 16) xs[c] = x[i * 16 + c];
    __syncthreads();
    float h = 0.f;
#pragma unroll
    for (int k = 0; k < 16; ++k) h += xs[k] * conv1_w[k * 128 + c];
    hs1[(size_t)i * 128 + c] = tob(dinv[i] * h);
    // gg branch: 16 -> 32 relu -> 16 relu
    if (c < 32) {
        float t = ln1_b[c];
#pragma unroll
        for (int k = 0; k < 16; ++k) t += xs[k] * ln1_w[k * 32 + c];
        t1[c] = fmaxf(t, 0.f);
    }
    __syncthreads();
    if (c < 16) {
        float t = ln2_b[c];
#pragma unroll
        for (int k = 0; k < 32; ++k) t += t1[k] * ln2_w[k * 16 + c];
        gg[(size_t)i * 16 + c] = fmaxf(t, 0.f);
    }
}

// ---------------- agg1: x1 = relu(agg(hs1)+b1); hs2 = dinv*(x1@conv2_w); a1 branch ----------------

__global__ __launch_bounds__(128) void agg1_kernel(
    const bf16* __restrict__ hs1, const int* __restrict__ offs, const int* __restrict__ csr,
    const float* __restrict__ dinv, const float* __restrict__ conv1_b,
    const float* __restrict__ conv2_w,
    const float* __restrict__ na1_w, const float* __restrict__ na1_b,
    const float* __restrict__ na2_w, const float* __restrict__ na2_b,
    bf16* __restrict__ hs2, float* __restrict__ a1, int n) {
    int i = blockIdx.x;
    if (i >= n) return;
    int c = threadIdx.x;
    __shared__ float x1s[128];
    __shared__ float t1s[16];
    float acc = tofb(hs1[(size_t)i * 128 + c]);  // self loop
    int e0 = offs[i], e1 = offs[i + 1];
    for (int e = e0; e < e1; ++e) {
        int j = csr[e];
        if ((unsigned)j < (unsigned)n) acc += tofb(hs1[(size_t)j * 128 + c]);
    }
    float x1 = fmaxf(dinv[i] * acc + conv1_b[c], 0.f);
    x1s[c] = x1;
    __syncthreads();
    float h = 0.f;
#pragma unroll 8
    for (int k = 0; k < 128; ++k) h += x1s[k] * conv2_w[k * 128 + c];
    hs2[(size_t)i * 128 + c] = tob(dinv[i] * h);
    // a1 branch: 128 -> 16 relu -> 16 relu
    if (c < 16) {
        float t = na1_b[c];
#pragma unroll 8
        for (int k = 0; k < 128; ++k) t += x1s[k] * na1_w[k * 16 + c];
        t1s[c] = fmaxf(t, 0.f);
    }
    __syncthreads();
    if (c < 16) {
        float t = na2_b[c];
#pragma unroll
        for (int k = 0; k < 16; ++k) t += t1s[k] * na2_w[k * 16 + c];
        a1[(size_t)i * 16 + c] = fmaxf(t, 0.f);
    }
}

// ---------------- agg2: x2 = relu(agg(hs2)+b2); a2 branch; head f1/f2/f3 -> sigmoid ----------------

__global__ __launch_bounds__(128) void agg2_kernel(
    const bf16* __restrict__ hs2, const int* __restrict__ offs, const int* __restrict__ csr,
    const float* __restrict__ dinv, const float* __restrict__ conv2_b,
    const float* __restrict__ na3_w, const float* __restrict__ na3_b,
    const float* __restrict__ na4_w, const float* __restrict__ na4_b,
    const float* __restrict__ gg, const float* __restrict__ a1,
    const float* __restrict__ f1_w, const float* __restrict__ f1_b,
    const float* __restrict__ f2_w, const float* __restrict__ f2_b,
    const float* __restrict__ f3_w, const float* __restrict__ f3_b,
    float* __restrict__ out, int n) {
    int i = blockIdx.x;
    if (i >= n) return;
    int c = threadIdx.x;
    __shared__ float x2s[128];
    __shared__ float t1s[16];
    __shared__ float xf[48];
    __shared__ float y1s[64];
    __shared__ float y2s[32];
    float acc = tofb(hs2[(size_t)i * 128 + c]);  // self loop
    int e0 = offs[i], e1 = offs[i + 1];
    for (int e = e0; e < e1; ++e) {
        int j = csr[e];
        if ((unsigned)j < (unsigned)n) acc += tofb(hs2[(size_t)j * 128 + c]);
    }
    float x2 = fmaxf(dinv[i] * acc + conv2_b[c], 0.f);
    x2s[c] = x2;
    __syncthreads();
    // a2 stage 1 (threads 0..15); meanwhile threads 32..63 load gg/a1 into xf
    if (c < 16) {
        float t = na3_b[c];
#pragma unroll 8
        for (int k = 0; k < 128; ++k) t += x2s[k] * na3_w[k * 16 + c];
        t1s[c] = fmaxf(t, 0.f);
    } else if (c >= 32 && c < 48) {
        xf[c - 32] = gg[(size_t)i * 16 + (c - 32)];
    } else if (c >= 48 && c < 64) {
        xf[c - 32] = a1[(size_t)i * 16 + (c - 48)];
    }
    __syncthreads();
    if (c < 16) {
        float t = na4_b[c];
#pragma unroll
        for (int k = 0; k < 16; ++k) t += t1s[k] * na4_w[k * 16 + c];
        xf[32 + c] = fmaxf(t, 0.f);
    }
    __syncthreads();
    if (c < 64) {
        float t = f1_b[c];
#pragma unroll 8
        for (int k = 0; k < 48; ++k) t += xf[k] * f1_w[k * 64 + c];
        y1s[c] = fmaxf(t, 0.f);
    }
    __syncthreads();
    if (c < 32) {
        float t = f2_b[c];
#pragma unroll 8
        for (int k = 0; k < 64; ++k) t += y1s[k] * f2_w[k * 32 + c];
        y2s[c] = fmaxf(t, 0.f);
    }
    __syncthreads();
    if (c == 0) {
        float z = f3_b[0];
#pragma unroll
        for (int k = 0; k < 32; ++k) z += y2s[k] * f3_w[k];
        out[i] = 1.f / (1.f + expf(-z));
    }
}

// ---------------- launch ----------------

extern "C" void kernel_launch(void* const* d_in, const int* in_sizes, int n_in,
                              void* d_out, int out_size, void* d_ws, size_t ws_size,
                              hipStream_t stream) {
    const float* x       = (const float*)d_in[0];
    const int*   eidx    = (const int*)d_in[1];
    const float* conv1_w = (const float*)d_in[2];
    const float* conv1_b = (const float*)d_in[3];
    const float* conv2_w = (const float*)d_in[4];
    const float* conv2_b = (const float*)d_in[5];
    const float* ln1_w   = (const float*)d_in[6];
    const float* ln1_b   = (const float*)d_in[7];
    const float* ln2_w   = (const float*)d_in[8];
    const float* ln2_b   = (const float*)d_in[9];
    const float* na1_w   = (const float*)d_in[10];
    const float* na1_b   = (const float*)d_in[11];
    const float* na2_w   = (const float*)d_in[12];
    const float* na2_b   = (const float*)d_in[13];
    const float* na3_w   = (const float*)d_in[14];
    const float* na3_b   = (const float*)d_in[15];
    const float* na4_w   = (const float*)d_in[16];
    const float* na4_b   = (const float*)d_in[17];
    const float* f1_w    = (const float*)d_in[18];
    const float* f1_b    = (const float*)d_in[19];
    const float* f2_w    = (const float*)d_in[20];
    const float* f2_b    = (const float*)d_in[21];
    const float* f3_w    = (const float*)d_in[22];
    const float* f3_b    = (const float*)d_in[23];

    const int N = in_sizes[0] / 16;
    const int E = in_sizes[1] / 2;

    // workspace carve-up (256B aligned) — total ~39 MB
    char* p = (char*)d_ws;
    auto alloc = [&](size_t bytes) {
        char* r = p;
        p += (bytes + 255) & ~(size_t)255;
        return r;
    };
    int*   cnt  = (int*)alloc((size_t)N * 4);          // doubles as scatter cursor
    int*   offs = (int*)alloc(((size_t)N + 1) * 4);
    int*   csr  = (int*)alloc((size_t)E * 4);
    float* dinv = (float*)alloc((size_t)N * 4);
    int*   flag = (int*)alloc(256);
    bf16*  hs1  = (bf16*)alloc((size_t)N * 128 * 2);
    bf16*  hs2  = (bf16*)alloc((size_t)N * 128 * 2);
    float* ggb  = (float*)alloc((size_t)N * 16 * 4);
    float* a1b  = (float*)alloc((size_t)N * 16 * 4);

    int eb = (E + 255) / 256;
    hipMemsetAsync(cnt, 0, (size_t)N * 4, stream);
    detect_kernel<<<1, 64, 0, stream>>>(eidx, flag);
    count_kernel<<<eb, 256, 0, stream>>>(eidx, flag, cnt, E, N);
    scan_kernel<<<1, SCAN_T, 0, stream>>>(cnt, offs, dinv, N);
    hipMemsetAsync(cnt, 0, (size_t)N * 4, stream);  // reuse as cursor
    scatter_kernel<<<eb, 256, 0, stream>>>(eidx, flag, offs, cnt, csr, E, N);

    pre_kernel<<<N, 128, 0, stream>>>(x, conv1_w, ln1_w, ln1_b, ln2_w, ln2_b, dinv, hs1, ggb, N);
    agg1_kernel<<<N, 128, 0, stream>>>(hs1, offs, csr, dinv, conv1_b, conv2_w,
                                       na1_w, na1_b, na2_w, na2_b, hs2, a1b, N);
    agg2_kernel<<<N, 128, 0, stream>>>(hs2, offs, csr, dinv, conv2_b,
                                       na3_w, na3_b, na4_w, na4_b, ggb, a1b,
                                       f1_w, f1_b, f2_w, f2_b, f3_w, f3_b,
                                       (float*)d_out, N);
}

// Round 4
// 832.052 us; speedup vs baseline: 1.1693x; 1.1693x over previous
//
#include <hip/hip_runtime.h>
#include <hip/hip_bf16.h>

typedef __hip_bfloat16 bf16;
__device__ __forceinline__ float tofb(bf16 v) { return __bfloat162float(v); }
__device__ __forceinline__ bf16 tob(float v) { return __float2bfloat16(v); }
// bf16x2 packed in a uint: low 16 bits = element 2m, high = element 2m+1
__device__ __forceinline__ float lo_f(unsigned v) { return __uint_as_float(v << 16); }
__device__ __forceinline__ float hi_f(unsigned v) { return __uint_as_float(v & 0xffff0000u); }
__device__ __forceinline__ unsigned f2bf_bits(float f) {  // RNE f32->bf16 bits
    unsigned u = __float_as_uint(f);
    return (u + 0x7fffu + ((u >> 16) & 1u)) >> 16;
}

#define SCAN_B 1024

// ---------------- edge-layout probe: int32 (stride 1) vs raw int64 (stride 2) ----------------
__global__ void detect_kernel(const int* __restrict__ e, int* __restrict__ flag) {
    if (threadIdx.x == 0 && blockIdx.x == 0) {
        int s = 0;
        for (int k = 1; k < 64; k += 2) s |= e[k];
        flag[0] = (s == 0) ? 2 : 1;
    }
}

// ---------------- CSR construction ----------------

__global__ __launch_bounds__(256) void count_kernel(const int* __restrict__ eidx,
                                                    const int* __restrict__ flag,
                                                    int* __restrict__ cnt, int E, int n) {
    int stride = flag[0];
    int e = blockIdx.x * 256 + threadIdx.x;
    if (e < E) {
        int d = eidx[(size_t)E * stride + (size_t)e * stride];  // dst row
        if ((unsigned)d < (unsigned)n) atomicAdd(&cnt[d], 1);
    }
}

// phase 1: per-block inclusive scan -> block-local exclusive into offs; block sum -> part; dinv
__global__ __launch_bounds__(SCAN_B) void scan_part_kernel(const int* __restrict__ cnt,
                                                           int* __restrict__ offs,
                                                           int* __restrict__ part,
                                                           float* __restrict__ dinv, int n) {
    __shared__ int s[SCAN_B];
    int i = blockIdx.x * SCAN_B + threadIdx.x;
    int v = (i < n) ? cnt[i] : 0;
    if (i < n) dinv[i] = rsqrtf((float)v + 1.0f);  // +1 self-loop
    s[threadIdx.x] = v;
    __syncthreads();
    for (int off = 1; off < SCAN_B; off <<= 1) {
        int t = (threadIdx.x >= off) ? s[threadIdx.x - off] : 0;
        __syncthreads();
        s[threadIdx.x] += t;
        __syncthreads();
    }
    if (i < n) offs[i] = s[threadIdx.x] - v;  // block-local exclusive
    if (threadIdx.x == SCAN_B - 1) part[blockIdx.x] = s[SCAN_B - 1];
}

// phase 2: serial exclusive scan of block partials (nb ~ 49); writes offs[n] = total
__global__ void scan_tops_kernel(int* __restrict__ part, int* __restrict__ offs_n, int nb) {
    if (threadIdx.x == 0 && blockIdx.x == 0) {
        int run = 0;
        for (int b = 0; b < nb; ++b) { int t = part[b]; part[b] = run; run += t; }
        offs_n[0] = run;
    }
}

// phase 3: add block base
__global__ __launch_bounds__(SCAN_B) void scan_apply_kernel(int* __restrict__ offs,
                                                            const int* __restrict__ part, int n) {
    int i = blockIdx.x * SCAN_B + threadIdx.x;
    if (i < n) offs[i] += part[blockIdx.x];
}

__global__ __launch_bounds__(256) void scatter_kernel(const int* __restrict__ eidx,
                                                      const int* __restrict__ flag,
                                                      const int* __restrict__ offs,
                                                      int* __restrict__ cursor,
                                                      int* __restrict__ csr, int E, int n) {
    int stride = flag[0];
    int e = blockIdx.x * 256 + threadIdx.x;
    if (e < E) {
        int d = eidx[(size_t)E * stride + (size_t)e * stride];
        int srcv = eidx[(size_t)e * stride];
        if ((unsigned)d < (unsigned)n && (unsigned)srcv < (unsigned)n) {
            int pos = atomicAdd(&cursor[d], 1);
            csr[offs[d] + pos] = srcv;
        }
    }
}

// ---------------- weight pack: conv2_w [128][128] f32 -> bf16x2 pairs over k ----------------
// w2p[m*128 + c] = pack(w[2m][c], w[2m+1][c]),  m in [0,64)
__global__ __launch_bounds__(256) void pack_w2_kernel(const float* __restrict__ w,
                                                      unsigned* __restrict__ wp) {
    int idx = blockIdx.x * 256 + threadIdx.x;
    if (idx < 64 * 128) {
        int m = idx >> 7, c = idx & 127;
        unsigned lo = f2bf_bits(w[(2 * m) * 128 + c]);
        unsigned hi = f2bf_bits(w[(2 * m + 1) * 128 + c]);
        wp[idx] = lo | (hi << 16);
    }
}

// ---------------- dense pre-pass: hs1 = dinv * (x @ conv1_w), gg branch ----------------

__global__ __launch_bounds__(128) void pre_kernel(
    const float* __restrict__ x, const float* __restrict__ conv1_w,
    const float* __restrict__ ln1_w, const float* __restrict__ ln1_b,
    const float* __restrict__ ln2_w, const float* __restrict__ ln2_b,
    const float* __restrict__ dinv,
    bf16* __restrict__ hs1, float* __restrict__ gg, int n) {
    int i = blockIdx.x;
    if (i >= n) return;
    int c = threadIdx.x;
    __shared__ float xs[16];
    __shared__ float t1[32];
    if (c < 16) xs[c] = x[i * 16 + c];
    __syncthreads();
    float h = 0.f;
#pragma unroll
    for (int k = 0; k < 16; ++k) h += xs[k] * conv1_w[k * 128 + c];
    hs1[(size_t)i * 128 + c] = tob(dinv[i] * h);
    if (c < 32) {
        float t = ln1_b[c];
#pragma unroll
        for (int k = 0; k < 16; ++k) t += xs[k] * ln1_w[k * 32 + c];
        t1[c] = fmaxf(t, 0.f);
    }
    __syncthreads();
    if (c < 16) {
        float t = ln2_b[c];
#pragma unroll
        for (int k = 0; k < 32; ++k) t += t1[k] * ln2_w[k * 16 + c];
        gg[(size_t)i * 16 + c] = fmaxf(t, 0.f);
    }
}

// gather helper: two waves split the edge list; each wave covers a full 128-col row
// via 4B bf16x2 loads (lane l -> cols 2l, 2l+1). comb[w][c] holds each wave's partial.
__device__ __forceinline__ void gather_rows(const bf16* __restrict__ hs, int i,
                                            const int* __restrict__ offs,
                                            const int* __restrict__ csr,
                                            float* comb0, float* comb1, int n) {
    int tid = threadIdx.x;
    int w = tid >> 6, l = tid & 63;
    float ax = 0.f, ay = 0.f;
    int e0 = offs[i], e1 = offs[i + 1];
    for (int e = e0 + w; e < e1; e += 2) {
        int j = csr[e];
        if ((unsigned)j < (unsigned)n) {
            unsigned v = *(const unsigned*)((const char*)hs + ((size_t)j * 256 + 4 * l));
            ax += lo_f(v);
            ay += hi_f(v);
        }
    }
    if (w == 0) {  // self loop
        unsigned v = *(const unsigned*)((const char*)hs + ((size_t)i * 256 + 4 * l));
        ax += lo_f(v);
        ay += hi_f(v);
    }
    float* dst = w ? comb1 : comb0;
    dst[2 * l] = ax;
    dst[2 * l + 1] = ay;
}

// ---------------- agg1: x1 = relu(agg(hs1)+b1); hs2 = dinv*(x1@W2); a1 branch ----------------

__global__ __launch_bounds__(128) void agg1_kernel(
    const bf16* __restrict__ hs1, const int* __restrict__ offs, const int* __restrict__ csr,
    const float* __restrict__ dinv, const float* __restrict__ conv1_b,
    const unsigned* __restrict__ w2p,
    const float* __restrict__ na1_w, const float* __restrict__ na1_b,
    const float* __restrict__ na2_w, const float* __restrict__ na2_b,
    bf16* __restrict__ hs2, float* __restrict__ a1, int n) {
    int i = blockIdx.x;
    if (i >= n) return;
    int c = threadIdx.x;
    __shared__ float comb0[128], comb1[128];
    __shared__ float x1s[128];
    __shared__ float t1s[16];
    gather_rows(hs1, i, offs, csr, comb0, comb1, n);
    __syncthreads();
    float x1 = fmaxf(dinv[i] * (comb0[c] + comb1[c]) + conv1_b[c], 0.f);
    x1s[c] = x1;
    __syncthreads();
    // conv2 matmul with bf16x2-packed weights (k-pairs)
    float h = 0.f;
#pragma unroll 8
    for (int m = 0; m < 64; ++m) {
        unsigned v = w2p[m * 128 + c];
        h += x1s[2 * m] * lo_f(v) + x1s[2 * m + 1] * hi_f(v);
    }
    hs2[(size_t)i * 128 + c] = tob(dinv[i] * h);
    // a1 branch: 128 -> 16 relu -> 16 relu
    if (c < 16) {
        float t = na1_b[c];
#pragma unroll 8
        for (int k = 0; k < 128; ++k) t += x1s[k] * na1_w[k * 16 + c];
        t1s[c] = fmaxf(t, 0.f);
    }
    __syncthreads();
    if (c < 16) {
        float t = na2_b[c];
#pragma unroll
        for (int k = 0; k < 16; ++k) t += t1s[k] * na2_w[k * 16 + c];
        a1[(size_t)i * 16 + c] = fmaxf(t, 0.f);
    }
}

// ---------------- agg2: x2 = relu(agg(hs2)+b2); a2 branch; head f1/f2/f3 -> sigmoid ----------------

__global__ __launch_bounds__(128) void agg2_kernel(
    const bf16* __restrict__ hs2, const int* __restrict__ offs, const int* __restrict__ csr,
    const float* __restrict__ dinv, const float* __restrict__ conv2_b,
    const float* __restrict__ na3_w, const float* __restrict__ na3_b,
    const float* __restrict__ na4_w, const float* __restrict__ na4_b,
    const float* __restrict__ gg, const float* __restrict__ a1,
    const float* __restrict__ f1_w, const float* __restrict__ f1_b,
    const float* __restrict__ f2_w, const float* __restrict__ f2_b,
    const float* __restrict__ f3_w, const float* __restrict__ f3_b,
    float* __restrict__ out, int n) {
    int i = blockIdx.x;
    if (i >= n) return;
    int c = threadIdx.x;
    __shared__ float comb0[128], comb1[128];
    __shared__ float x2s[128];
    __shared__ float t1s[16];
    __shared__ float xf[48];
    __shared__ float y1s[64];
    __shared__ float y2s[32];
    gather_rows(hs2, i, offs, csr, comb0, comb1, n);
    __syncthreads();
    float x2 = fmaxf(dinv[i] * (comb0[c] + comb1[c]) + conv2_b[c], 0.f);
    x2s[c] = x2;
    __syncthreads();
    // a2 stage 1 (threads 0..15); threads 32..63 load gg/a1 into xf
    if (c < 16) {
        float t = na3_b[c];
#pragma unroll 8
        for (int k = 0; k < 128; ++k) t += x2s[k] * na3_w[k * 16 + c];
        t1s[c] = fmaxf(t, 0.f);
    } else if (c >= 32 && c < 48) {
        xf[c - 32] = gg[(size_t)i * 16 + (c - 32)];
    } else if (c >= 48 && c < 64) {
        xf[c - 32] = a1[(size_t)i * 16 + (c - 48)];
    }
    __syncthreads();
    if (c < 16) {
        float t = na4_b[c];
#pragma unroll
        for (int k = 0; k < 16; ++k) t += t1s[k] * na4_w[k * 16 + c];
        xf[32 + c] = fmaxf(t, 0.f);
    }
    __syncthreads();
    if (c < 64) {
        float t = f1_b[c];
#pragma unroll 8
        for (int k = 0; k < 48; ++k) t += xf[k] * f1_w[k * 64 + c];
        y1s[c] = fmaxf(t, 0.f);
    }
    __syncthreads();
    if (c < 32) {
        float t = f2_b[c];
#pragma unroll 8
        for (int k = 0; k < 64; ++k) t += y1s[k] * f2_w[k * 32 + c];
        y2s[c] = fmaxf(t, 0.f);
    }
    __syncthreads();
    if (c == 0) {
        float z = f3_b[0];
#pragma unroll
        for (int k = 0; k < 32; ++k) z += y2s[k] * f3_w[k];
        out[i] = 1.f / (1.f + expf(-z));
    }
}

// ---------------- launch ----------------

extern "C" void kernel_launch(void* const* d_in, const int* in_sizes, int n_in,
                              void* d_out, int out_size, void* d_ws, size_t ws_size,
                              hipStream_t stream) {
    const float* x       = (const float*)d_in[0];
    const int*   eidx    = (const int*)d_in[1];
    const float* conv1_w = (const float*)d_in[2];
    const float* conv1_b = (const float*)d_in[3];
    const float* conv2_w = (const float*)d_in[4];
    const float* conv2_b = (const float*)d_in[5];
    const float* ln1_w   = (const float*)d_in[6];
    const float* ln1_b   = (const float*)d_in[7];
    const float* ln2_w   = (const float*)d_in[8];
    const float* ln2_b   = (const float*)d_in[9];
    const float* na1_w   = (const float*)d_in[10];
    const float* na1_b   = (const float*)d_in[11];
    const float* na2_w   = (const float*)d_in[12];
    const float* na2_b   = (const float*)d_in[13];
    const float* na3_w   = (const float*)d_in[14];
    const float* na3_b   = (const float*)d_in[15];
    const float* na4_w   = (const float*)d_in[16];
    const float* na4_b   = (const float*)d_in[17];
    const float* f1_w    = (const float*)d_in[18];
    const float* f1_b    = (const float*)d_in[19];
    const float* f2_w    = (const float*)d_in[20];
    const float* f2_b    = (const float*)d_in[21];
    const float* f3_w    = (const float*)d_in[22];
    const float* f3_b    = (const float*)d_in[23];

    const int N = in_sizes[0] / 16;
    const int E = in_sizes[1] / 2;
    const int NB = (N + SCAN_B - 1) / SCAN_B;

    // workspace carve-up (256B aligned) — ~39 MB
    char* p = (char*)d_ws;
    auto alloc = [&](size_t bytes) {
        char* r = p;
        p += (bytes + 255) & ~(size_t)255;
        return r;
    };
    int*      cnt  = (int*)alloc((size_t)N * 4);          // doubles as scatter cursor
    int*      offs = (int*)alloc(((size_t)N + 1) * 4);
    int*      csr  = (int*)alloc((size_t)E * 4);
    float*    dinv = (float*)alloc((size_t)N * 4);
    int*      flag = (int*)alloc(256);
    int*      part = (int*)alloc((size_t)NB * 4);
    unsigned* w2p  = (unsigned*)alloc((size_t)64 * 128 * 4);
    bf16*     hs1  = (bf16*)alloc((size_t)N * 128 * 2);
    bf16*     hs2  = (bf16*)alloc((size_t)N * 128 * 2);
    float*    ggb  = (float*)alloc((size_t)N * 16 * 4);
    float*    a1b  = (float*)alloc((size_t)N * 16 * 4);

    int eb = (E + 255) / 256;
    hipMemsetAsync(cnt, 0, (size_t)N * 4, stream);
    detect_kernel<<<1, 64, 0, stream>>>(eidx, flag);
    count_kernel<<<eb, 256, 0, stream>>>(eidx, flag, cnt, E, N);
    scan_part_kernel<<<NB, SCAN_B, 0, stream>>>(cnt, offs, part, dinv, N);
    scan_tops_kernel<<<1, 64, 0, stream>>>(part, offs + N, NB);
    scan_apply_kernel<<<NB, SCAN_B, 0, stream>>>(offs, part, N);
    hipMemsetAsync(cnt, 0, (size_t)N * 4, stream);  // reuse as cursor
    scatter_kernel<<<eb, 256, 0, stream>>>(eidx, flag, offs, cnt, csr, E, N);

    pack_w2_kernel<<<32, 256, 0, stream>>>(conv2_w, w2p);
    pre_kernel<<<N, 128, 0, stream>>>(x, conv1_w, ln1_w, ln1_b, ln2_w, ln2_b, dinv, hs1, ggb, N);
    agg1_kernel<<<N, 128, 0, stream>>>(hs1, offs, csr, dinv, conv1_b, w2p,
                                       na1_w, na1_b, na2_w, na2_b, hs2, a1b, N);
    agg2_kernel<<<N, 128, 0, stream>>>(hs2, offs, csr, dinv, conv2_b,
                                       na3_w, na3_b, na4_w, na4_b, ggb, a1b,
                                       f1_w, f1_b, f2_w, f2_b, f3_w, f3_b,
                                       (float*)d_out, N);
}

// Round 5
// 676.547 us; speedup vs baseline: 1.4381x; 1.2299x over previous
//
#include <hip/hip_runtime.h>
#include <hip/hip_bf16.h>

typedef __hip_bfloat16 bf16;
__device__ __forceinline__ float tofb(bf16 v) { return __bfloat162float(v); }
__device__ __forceinline__ bf16 tob(float v) { return __float2bfloat16(v); }
// bf16x2 packed in a uint: low 16 bits = element 2m, high = element 2m+1
__device__ __forceinline__ float lo_f(unsigned v) { return __uint_as_float(v << 16); }
__device__ __forceinline__ float hi_f(unsigned v) { return __uint_as_float(v & 0xffff0000u); }
__device__ __forceinline__ unsigned f2bf_bits(float f) {  // RNE f32->bf16 bits
    unsigned u = __float_as_uint(f);
    return (u + 0x7fffu + ((u >> 16) & 1u)) >> 16;
}

#define SCAN_B 1024

// ---------------- edge-layout probe: int32 (stride 1) vs raw int64 (stride 2) ----------------
__global__ void detect_kernel(const int* __restrict__ e, int* __restrict__ flag) {
    if (threadIdx.x == 0 && blockIdx.x == 0) {
        int s = 0;
        for (int k = 1; k < 64; k += 2) s |= e[k];
        flag[0] = (s == 0) ? 2 : 1;
    }
}

// ---------------- CSR construction ----------------

__global__ __launch_bounds__(256) void count_kernel(const int* __restrict__ eidx,
                                                    const int* __restrict__ flag,
                                                    int* __restrict__ cnt, int E, int n) {
    int stride = flag[0];
    int e = blockIdx.x * 256 + threadIdx.x;
    if (e < E) {
        int d = eidx[(size_t)E * stride + (size_t)e * stride];  // dst row
        if ((unsigned)d < (unsigned)n) atomicAdd(&cnt[d], 1);
    }
}

// phase 1: per-block inclusive scan -> block-local exclusive into offs; block sum -> part; dinv
__global__ __launch_bounds__(SCAN_B) void scan_part_kernel(const int* __restrict__ cnt,
                                                           int* __restrict__ offs,
                                                           int* __restrict__ part,
                                                           float* __restrict__ dinv, int n) {
    __shared__ int s[SCAN_B];
    int i = blockIdx.x * SCAN_B + threadIdx.x;
    int v = (i < n) ? cnt[i] : 0;
    if (i < n) dinv[i] = rsqrtf((float)v + 1.0f);  // +1 self-loop
    s[threadIdx.x] = v;
    __syncthreads();
    for (int off = 1; off < SCAN_B; off <<= 1) {
        int t = (threadIdx.x >= off) ? s[threadIdx.x - off] : 0;
        __syncthreads();
        s[threadIdx.x] += t;
        __syncthreads();
    }
    if (i < n) offs[i] = s[threadIdx.x] - v;  // block-local exclusive
    if (threadIdx.x == SCAN_B - 1) part[blockIdx.x] = s[SCAN_B - 1];
}

// phase 2: serial exclusive scan of block partials; writes offs[n] = total
__global__ void scan_tops_kernel(int* __restrict__ part, int* __restrict__ offs_n, int nb) {
    if (threadIdx.x == 0 && blockIdx.x == 0) {
        int run = 0;
        for (int b = 0; b < nb; ++b) { int t = part[b]; part[b] = run; run += t; }
        offs_n[0] = run;
    }
}

// phase 3: add block base
__global__ __launch_bounds__(SCAN_B) void scan_apply_kernel(int* __restrict__ offs,
                                                            const int* __restrict__ part, int n) {
    int i = blockIdx.x * SCAN_B + threadIdx.x;
    if (i < n) offs[i] += part[blockIdx.x];
}

__global__ __launch_bounds__(256) void scatter_kernel(const int* __restrict__ eidx,
                                                      const int* __restrict__ flag,
                                                      const int* __restrict__ offs,
                                                      int* __restrict__ cursor,
                                                      int* __restrict__ csr, int E, int n) {
    int stride = flag[0];
    int e = blockIdx.x * 256 + threadIdx.x;
    if (e < E) {
        int d = eidx[(size_t)E * stride + (size_t)e * stride];
        int srcv = eidx[(size_t)e * stride];
        if ((unsigned)d < (unsigned)n && (unsigned)srcv < (unsigned)n) {
            int pos = atomicAdd(&cursor[d], 1);
            csr[offs[d] + pos] = srcv;
        }
    }
}

// ---------------- weight pack: conv2_w [128][128] f32 -> bf16x2 pairs over k ----------------
__global__ __launch_bounds__(256) void pack_w2_kernel(const float* __restrict__ w,
                                                      unsigned* __restrict__ wp) {
    int idx = blockIdx.x * 256 + threadIdx.x;
    if (idx < 64 * 128) {
        int m = idx >> 7, c = idx & 127;
        unsigned lo = f2bf_bits(w[(2 * m) * 128 + c]);
        unsigned hi = f2bf_bits(w[(2 * m + 1) * 128 + c]);
        wp[idx] = lo | (hi << 16);
    }
}

// ---------------- dense pre-pass: hs1 = dinv * (x @ conv1_w), gg branch ----------------

__global__ __launch_bounds__(128) void pre_kernel(
    const float* __restrict__ x, const float* __restrict__ conv1_w,
    const float* __restrict__ ln1_w, const float* __restrict__ ln1_b,
    const float* __restrict__ ln2_w, const float* __restrict__ ln2_b,
    const float* __restrict__ dinv,
    bf16* __restrict__ hs1, float* __restrict__ gg, int n) {
    int i = blockIdx.x;
    if (i >= n) return;
    int c = threadIdx.x;
    __shared__ float xs[16];
    __shared__ float t1[32];
    if (c < 16) xs[c] = x[i * 16 + c];
    __syncthreads();
    float h = 0.f;
#pragma unroll
    for (int k = 0; k < 16; ++k) h += xs[k] * conv1_w[k * 128 + c];
    hs1[(size_t)i * 128 + c] = tob(dinv[i] * h);
    if (c < 32) {
        float t = ln1_b[c];
#pragma unroll
        for (int k = 0; k < 16; ++k) t += xs[k] * ln1_w[k * 32 + c];
        t1[c] = fmaxf(t, 0.f);
    }
    __syncthreads();
    if (c < 16) {
        float t = ln2_b[c];
#pragma unroll
        for (int k = 0; k < 32; ++k) t += t1[k] * ln2_w[k * 16 + c];
        gg[(size_t)i * 16 + c] = fmaxf(t, 0.f);
    }
}

// gather v2: lane-split rows. Each lane loads 16B (uint4) of a 256B row; 16 lanes/row,
// 4 rows per wave-iteration, 2 waves -> 8 edges in flight per block. 8 f32 accs/lane
// (cols sl*8..sl*8+7). Partials reduced via LDS [8][128].
__device__ __forceinline__ void gather_rows_v2(const bf16* __restrict__ hs, int i,
                                               const int* __restrict__ offs,
                                               const int* __restrict__ csr,
                                               float* __restrict__ partial, int n) {
    int tid = threadIdx.x;
    int w = tid >> 6, l = tid & 63;
    int g = l >> 4, sl = l & 15;
    int p = w * 4 + g;
    float a0 = 0.f, a1 = 0.f, a2 = 0.f, a3 = 0.f, a4 = 0.f, a5 = 0.f, a6 = 0.f, a7 = 0.f;
    int e0 = offs[i], e1 = offs[i + 1];
    for (int base = e0 + w * 4; base < e1; base += 8) {
        int e = base + g;
        if (e < e1) {
            int j = csr[e];
            uint4 v = *(const uint4*)((const char*)hs + ((size_t)j * 256 + sl * 16));
            a0 += lo_f(v.x); a1 += hi_f(v.x);
            a2 += lo_f(v.y); a3 += hi_f(v.y);
            a4 += lo_f(v.z); a5 += hi_f(v.z);
            a6 += lo_f(v.w); a7 += hi_f(v.w);
        }
    }
    if (p == 0) {  // self loop once
        uint4 v = *(const uint4*)((const char*)hs + ((size_t)i * 256 + sl * 16));
        a0 += lo_f(v.x); a1 += hi_f(v.x);
        a2 += lo_f(v.y); a3 += hi_f(v.y);
        a4 += lo_f(v.z); a5 += hi_f(v.z);
        a6 += lo_f(v.w); a7 += hi_f(v.w);
    }
    float* dst = partial + p * 128 + sl * 8;
    dst[0] = a0; dst[1] = a1; dst[2] = a2; dst[3] = a3;
    dst[4] = a4; dst[5] = a5; dst[6] = a6; dst[7] = a7;
}

// ---------------- agg1: x1 = relu(agg(hs1)+b1); hs2 = dinv*(x1@W2); a1 branch ----------------

__global__ __launch_bounds__(128) void agg1_kernel(
    const bf16* __restrict__ hs1, const int* __restrict__ offs, const int* __restrict__ csr,
    const float* __restrict__ dinv, const float* __restrict__ conv1_b,
    const unsigned* __restrict__ w2p,
    const float* __restrict__ na1_w, const float* __restrict__ na1_b,
    const float* __restrict__ na2_w, const float* __restrict__ na2_b,
    bf16* __restrict__ hs2, float* __restrict__ a1, int n) {
    int i = blockIdx.x;
    if (i >= n) return;
    int c = threadIdx.x;
    __shared__ float partial[8 * 128];
    __shared__ float x1s[128];
    __shared__ float t1s[16];
    gather_rows_v2(hs1, i, offs, csr, partial, n);
    __syncthreads();
    float s = 0.f;
#pragma unroll
    for (int q = 0; q < 8; ++q) s += partial[q * 128 + c];
    float x1 = fmaxf(dinv[i] * s + conv1_b[c], 0.f);
    x1s[c] = x1;
    __syncthreads();
    // conv2 matmul with bf16x2-packed weights (k-pairs)
    float h = 0.f;
#pragma unroll 8
    for (int m = 0; m < 64; ++m) {
        unsigned v = w2p[m * 128 + c];
        h += x1s[2 * m] * lo_f(v) + x1s[2 * m + 1] * hi_f(v);
    }
    hs2[(size_t)i * 128 + c] = tob(dinv[i] * h);
    // a1 branch: 128 -> 16 relu -> 16 relu
    if (c < 16) {
        float t = na1_b[c];
#pragma unroll 8
        for (int k = 0; k < 128; ++k) t += x1s[k] * na1_w[k * 16 + c];
        t1s[c] = fmaxf(t, 0.f);
    }
    __syncthreads();
    if (c < 16) {
        float t = na2_b[c];
#pragma unroll
        for (int k = 0; k < 16; ++k) t += t1s[k] * na2_w[k * 16 + c];
        a1[(size_t)i * 16 + c] = fmaxf(t, 0.f);
    }
}

// ---------------- agg2: x2 = relu(agg(hs2)+b2); a2 branch; head f1/f2/f3 -> sigmoid ----------------

__global__ __launch_bounds__(128) void agg2_kernel(
    const bf16* __restrict__ hs2, const int* __restrict__ offs, const int* __restrict__ csr,
    const float* __restrict__ dinv, const float* __restrict__ conv2_b,
    const float* __restrict__ na3_w, const float* __restrict__ na3_b,
    const float* __restrict__ na4_w, const float* __restrict__ na4_b,
    const float* __restrict__ gg, const float* __restrict__ a1,
    const float* __restrict__ f1_w, const float* __restrict__ f1_b,
    const float* __restrict__ f2_w, const float* __restrict__ f2_b,
    const float* __restrict__ f3_w, const float* __restrict__ f3_b,
    float* __restrict__ out, int n) {
    int i = blockIdx.x;
    if (i >= n) return;
    int c = threadIdx.x;
    __shared__ float partial[8 * 128];
    __shared__ float x2s[128];
    __shared__ float t1s[16];
    __shared__ float xf[48];
    __shared__ float y1s[64];
    __shared__ float y2s[32];
    gather_rows_v2(hs2, i, offs, csr, partial, n);
    __syncthreads();
    float s = 0.f;
#pragma unroll
    for (int q = 0; q < 8; ++q) s += partial[q * 128 + c];
    float x2 = fmaxf(dinv[i] * s + conv2_b[c], 0.f);
    x2s[c] = x2;
    __syncthreads();
    // a2 stage 1 (threads 0..15); threads 32..63 load gg/a1 into xf
    if (c < 16) {
        float t = na3_b[c];
#pragma unroll 8
        for (int k = 0; k < 128; ++k) t += x2s[k] * na3_w[k * 16 + c];
        t1s[c] = fmaxf(t, 0.f);
    } else if (c >= 32 && c < 48) {
        xf[c - 32] = gg[(size_t)i * 16 + (c - 32)];
    } else if (c >= 48 && c < 64) {
        xf[c - 32] = a1[(size_t)i * 16 + (c - 48)];
    }
    __syncthreads();
    if (c < 16) {
        float t = na4_b[c];
#pragma unroll
        for (int k = 0; k < 16; ++k) t += t1s[k] * na4_w[k * 16 + c];
        xf[32 + c] = fmaxf(t, 0.f);
    }
    __syncthreads();
    if (c < 64) {
        float t = f1_b[c];
#pragma unroll 8
        for (int k = 0; k < 48; ++k) t += xf[k] * f1_w[k * 64 + c];
        y1s[c] = fmaxf(t, 0.f);
    }
    __syncthreads();
    if (c < 32) {
        float t = f2_b[c];
#pragma unroll 8
        for (int k = 0; k < 64; ++k) t += y1s[k] * f2_w[k * 32 + c];
        y2s[c] = fmaxf(t, 0.f);
    }
    __syncthreads();
    if (c == 0) {
        float z = f3_b[0];
#pragma unroll
        for (int k = 0; k < 32; ++k) z += y2s[k] * f3_w[k];
        out[i] = 1.f / (1.f + expf(-z));
    }
}

// ---------------- launch ----------------

extern "C" void kernel_launch(void* const* d_in, const int* in_sizes, int n_in,
                              void* d_out, int out_size, void* d_ws, size_t ws_size,
                              hipStream_t stream) {
    const float* x       = (const float*)d_in[0];
    const int*   eidx    = (const int*)d_in[1];
    const float* conv1_w = (const float*)d_in[2];
    const float* conv1_b = (const float*)d_in[3];
    const float* conv2_w = (const float*)d_in[4];
    const float* conv2_b = (const float*)d_in[5];
    const float* ln1_w   = (const float*)d_in[6];
    const float* ln1_b   = (const float*)d_in[7];
    const float* ln2_w   = (const float*)d_in[8];
    const float* ln2_b   = (const float*)d_in[9];
    const float* na1_w   = (const float*)d_in[10];
    const float* na1_b   = (const float*)d_in[11];
    const float* na2_w   = (const float*)d_in[12];
    const float* na2_b   = (const float*)d_in[13];
    const float* na3_w   = (const float*)d_in[14];
    const float* na3_b   = (const float*)d_in[15];
    const float* na4_w   = (const float*)d_in[16];
    const float* na4_b   = (const float*)d_in[17];
    const float* f1_w    = (const float*)d_in[18];
    const float* f1_b    = (const float*)d_in[19];
    const float* f2_w    = (const float*)d_in[20];
    const float* f2_b    = (const float*)d_in[21];
    const float* f3_w    = (const float*)d_in[22];
    const float* f3_b    = (const float*)d_in[23];

    const int N = in_sizes[0] / 16;
    const int E = in_sizes[1] / 2;
    const int NB = (N + SCAN_B - 1) / SCAN_B;

    // workspace carve-up (256B aligned) — ~39 MB
    char* p = (char*)d_ws;
    auto alloc = [&](size_t bytes) {
        char* r = p;
        p += (bytes + 255) & ~(size_t)255;
        return r;
    };
    int*      cnt  = (int*)alloc((size_t)N * 4);          // doubles as scatter cursor
    int*      offs = (int*)alloc(((size_t)N + 1) * 4);
    int*      csr  = (int*)alloc((size_t)E * 4);
    float*    dinv = (float*)alloc((size_t)N * 4);
    int*      flag = (int*)alloc(256);
    int*      part = (int*)alloc((size_t)NB * 4);
    unsigned* w2p  = (unsigned*)alloc((size_t)64 * 128 * 4);
    bf16*     hs1  = (bf16*)alloc((size_t)N * 128 * 2);
    bf16*     hs2  = (bf16*)alloc((size_t)N * 128 * 2);
    float*    ggb  = (float*)alloc((size_t)N * 16 * 4);
    float*    a1b  = (float*)alloc((size_t)N * 16 * 4);

    int eb = (E + 255) / 256;
    hipMemsetAsync(cnt, 0, (size_t)N * 4, stream);
    detect_kernel<<<1, 64, 0, stream>>>(eidx, flag);
    count_kernel<<<eb, 256, 0, stream>>>(eidx, flag, cnt, E, N);
    scan_part_kernel<<<NB, SCAN_B, 0, stream>>>(cnt, offs, part, dinv, N);
    scan_tops_kernel<<<1, 64, 0, stream>>>(part, offs + N, NB);
    scan_apply_kernel<<<NB, SCAN_B, 0, stream>>>(offs, part, N);
    hipMemsetAsync(cnt, 0, (size_t)N * 4, stream);  // reuse as cursor
    scatter_kernel<<<eb, 256, 0, stream>>>(eidx, flag, offs, cnt, csr, E, N);

    pack_w2_kernel<<<32, 256, 0, stream>>>(conv2_w, w2p);
    pre_kernel<<<N, 128, 0, stream>>>(x, conv1_w, ln1_w, ln1_b, ln2_w, ln2_b, dinv, hs1, ggb, N);
    agg1_kernel<<<N, 128, 0, stream>>>(hs1, offs, csr, dinv, conv1_b, w2p,
                                       na1_w, na1_b, na2_w, na2_b, hs2, a1b, N);
    agg2_kernel<<<N, 128, 0, stream>>>(hs2, offs, csr, dinv, conv2_b,
                                       na3_w, na3_b, na4_w, na4_b, ggb, a1b,
                                       f1_w, f1_b, f2_w, f2_b, f3_w, f3_b,
                                       (float*)d_out, N);
}

// Round 6
// 621.046 us; speedup vs baseline: 1.5666x; 1.0894x over previous
//
#include <hip/hip_runtime.h>
#include <hip/hip_bf16.h>

typedef __hip_bfloat16 bf16;
__device__ __forceinline__ float tofb(bf16 v) { return __bfloat162float(v); }
__device__ __forceinline__ bf16 tob(float v) { return __float2bfloat16(v); }
// bf16x2 packed in a uint: low 16 bits = element 2m, high = element 2m+1
__device__ __forceinline__ float lo_f(unsigned v) { return __uint_as_float(v << 16); }
__device__ __forceinline__ float hi_f(unsigned v) { return __uint_as_float(v & 0xffff0000u); }
__device__ __forceinline__ unsigned f2bf_bits(float f) {  // RNE f32->bf16 bits
    unsigned u = __float_as_uint(f);
    return (u + 0x7fffu + ((u >> 16) & 1u)) >> 16;
}

#define SCAN_B 1024

// ---------------- edge-layout probe: int32 (stride 1) vs raw int64 (stride 2) ----------------
__global__ void detect_kernel(const int* __restrict__ e, int* __restrict__ flag) {
    if (threadIdx.x == 0 && blockIdx.x == 0) {
        int s = 0;
        for (int k = 1; k < 64; k += 2) s |= e[k];
        flag[0] = (s == 0) ? 2 : 1;
    }
}

// ---------------- CSR construction ----------------

__global__ __launch_bounds__(256) void count_kernel(const int* __restrict__ eidx,
                                                    const int* __restrict__ flag,
                                                    int* __restrict__ cnt, int E, int n) {
    int stride = flag[0];
    int e = blockIdx.x * 256 + threadIdx.x;
    if (e < E) {
        int d = eidx[(size_t)E * stride + (size_t)e * stride];  // dst row
        if ((unsigned)d < (unsigned)n) atomicAdd(&cnt[d], 1);
    }
}

// phase 1: per-block inclusive scan -> block-local exclusive into offs; block sum -> part; dinv
__global__ __launch_bounds__(SCAN_B) void scan_part_kernel(const int* __restrict__ cnt,
                                                           int* __restrict__ offs,
                                                           int* __restrict__ part,
                                                           float* __restrict__ dinv, int n) {
    __shared__ int s[SCAN_B];
    int i = blockIdx.x * SCAN_B + threadIdx.x;
    int v = (i < n) ? cnt[i] : 0;
    if (i < n) dinv[i] = rsqrtf((float)v + 1.0f);  // +1 self-loop
    s[threadIdx.x] = v;
    __syncthreads();
    for (int off = 1; off < SCAN_B; off <<= 1) {
        int t = (threadIdx.x >= off) ? s[threadIdx.x - off] : 0;
        __syncthreads();
        s[threadIdx.x] += t;
        __syncthreads();
    }
    if (i < n) offs[i] = s[threadIdx.x] - v;  // block-local exclusive
    if (threadIdx.x == SCAN_B - 1) part[blockIdx.x] = s[SCAN_B - 1];
}

// phase 2: serial exclusive scan of block partials; writes offs[n] = total
__global__ void scan_tops_kernel(int* __restrict__ part, int* __restrict__ offs_n, int nb) {
    if (threadIdx.x == 0 && blockIdx.x == 0) {
        int run = 0;
        for (int b = 0; b < nb; ++b) { int t = part[b]; part[b] = run; run += t; }
        offs_n[0] = run;
    }
}

// phase 3: add block base
__global__ __launch_bounds__(SCAN_B) void scan_apply_kernel(int* __restrict__ offs,
                                                            const int* __restrict__ part, int n) {
    int i = blockIdx.x * SCAN_B + threadIdx.x;
    if (i < n) offs[i] += part[blockIdx.x];
}

__global__ __launch_bounds__(256) void scatter_kernel(const int* __restrict__ eidx,
                                                      const int* __restrict__ flag,
                                                      const int* __restrict__ offs,
                                                      int* __restrict__ cursor,
                                                      int* __restrict__ csr, int E, int n) {
    int stride = flag[0];
    int e = blockIdx.x * 256 + threadIdx.x;
    if (e < E) {
        int d = eidx[(size_t)E * stride + (size_t)e * stride];
        int srcv = eidx[(size_t)e * stride];
        if ((unsigned)d < (unsigned)n && (unsigned)srcv < (unsigned)n) {
            int pos = atomicAdd(&cursor[d], 1);
            csr[offs[d] + pos] = srcv;
        }
    }
}

// ---------------- weight pack: conv2_w [128][128] f32 -> bf16x2 pairs over k ----------------
__global__ __launch_bounds__(256) void pack_w2_kernel(const float* __restrict__ w,
                                                      unsigned* __restrict__ wp) {
    int idx = blockIdx.x * 256 + threadIdx.x;
    if (idx < 64 * 128) {
        int m = idx >> 7, c = idx & 127;
        unsigned lo = f2bf_bits(w[(2 * m) * 128 + c]);
        unsigned hi = f2bf_bits(w[(2 * m + 1) * 128 + c]);
        wp[idx] = lo | (hi << 16);
    }
}

// ---------------- dense pre-pass: hs1 = dinv * (x @ conv1_w), gg branch ----------------

__global__ __launch_bounds__(128) void pre_kernel(
    const float* __restrict__ x, const float* __restrict__ conv1_w,
    const float* __restrict__ ln1_w, const float* __restrict__ ln1_b,
    const float* __restrict__ ln2_w, const float* __restrict__ ln2_b,
    const float* __restrict__ dinv,
    bf16* __restrict__ hs1, float* __restrict__ gg, int n) {
    int i = blockIdx.x;
    if (i >= n) return;
    int c = threadIdx.x;
    __shared__ float xs[16];
    __shared__ float t1[32];
    if (c < 16) xs[c] = x[i * 16 + c];
    __syncthreads();
    float h = 0.f;
#pragma unroll
    for (int k = 0; k < 16; ++k) h += xs[k] * conv1_w[k * 128 + c];
    hs1[(size_t)i * 128 + c] = tob(dinv[i] * h);
    if (c < 32) {
        float t = ln1_b[c];
#pragma unroll
        for (int k = 0; k < 16; ++k) t += xs[k] * ln1_w[k * 32 + c];
        t1[c] = fmaxf(t, 0.f);
    }
    __syncthreads();
    if (c < 16) {
        float t = ln2_b[c];
#pragma unroll
        for (int k = 0; k < 32; ++k) t += t1[k] * ln2_w[k * 16 + c];
        gg[(size_t)i * 16 + c] = fmaxf(t, 0.f);
    }
}

// gather v3: CSR indices staged in LDS (block-wide coalesced load), then row loop with
// manual unroll-by-4. Each lane loads 16B of a 256B row (16 lanes/row); per wave 4 row
// groups x 4 unroll = 16 rows in flight. 8 f32 accs/lane; partials reduced via LDS [8][128].
#define ACC8(v)                              \
    a0 += lo_f((v).x); a1 += hi_f((v).x);    \
    a2 += lo_f((v).y); a3 += hi_f((v).y);    \
    a4 += lo_f((v).z); a5 += hi_f((v).z);    \
    a6 += lo_f((v).w); a7 += hi_f((v).w);

__device__ __forceinline__ void gather_rows_v3(const bf16* __restrict__ hs, int i,
                                               const int* __restrict__ offs,
                                               const int* __restrict__ csr,
                                               int* __restrict__ idxs,
                                               float* __restrict__ partial) {
    int tid = threadIdx.x;
    int w = tid >> 6, l = tid & 63;
    int g = l >> 4, sl = l & 15;
    int p = w * 4 + g;                 // row-group 0..7
    const char* base = (const char*)hs;
    int off16 = sl * 16;
    float a0 = 0.f, a1 = 0.f, a2 = 0.f, a3 = 0.f, a4 = 0.f, a5 = 0.f, a6 = 0.f, a7 = 0.f;
    int e0 = offs[i], e1 = offs[i + 1];
    for (int cb = e0; cb < e1; cb += 128) {
        int m = e1 - cb; if (m > 128) m = 128;
        if (tid < m) idxs[tid] = csr[cb + tid];
        __syncthreads();
        int t = p;
        for (; t + 24 < m; t += 32) {   // 4 rows per group per iter
            int j0 = idxs[t], j1 = idxs[t + 8], j2 = idxs[t + 16], j3 = idxs[t + 24];
            uint4 v0 = *(const uint4*)(base + ((size_t)j0 * 256 + off16));
            uint4 v1 = *(const uint4*)(base + ((size_t)j1 * 256 + off16));
            uint4 v2 = *(const uint4*)(base + ((size_t)j2 * 256 + off16));
            uint4 v3 = *(const uint4*)(base + ((size_t)j3 * 256 + off16));
            ACC8(v0) ACC8(v1) ACC8(v2) ACC8(v3)
        }
        for (; t < m; t += 8) {
            int j = idxs[t];
            uint4 v = *(const uint4*)(base + ((size_t)j * 256 + off16));
            ACC8(v)
        }
        __syncthreads();
    }
    if (p == 0) {  // self loop once
        uint4 v = *(const uint4*)(base + ((size_t)i * 256 + off16));
        ACC8(v)
    }
    float* dst = partial + p * 128 + sl * 8;
    dst[0] = a0; dst[1] = a1; dst[2] = a2; dst[3] = a3;
    dst[4] = a4; dst[5] = a5; dst[6] = a6; dst[7] = a7;
}

// ---------------- agg1: x1 = relu(agg(hs1)+b1); hs2 = dinv*(x1@W2); a1 branch ----------------

__global__ __launch_bounds__(128) void agg1_kernel(
    const bf16* __restrict__ hs1, const int* __restrict__ offs, const int* __restrict__ csr,
    const float* __restrict__ dinv, const float* __restrict__ conv1_b,
    const unsigned* __restrict__ w2p,
    const float* __restrict__ na1_w, const float* __restrict__ na1_b,
    const float* __restrict__ na2_w, const float* __restrict__ na2_b,
    bf16* __restrict__ hs2, float* __restrict__ a1, int n) {
    int i = blockIdx.x;
    if (i >= n) return;
    int c = threadIdx.x;
    __shared__ int idxs[128];
    __shared__ float partial[8 * 128];
    __shared__ float x1s[128];
    __shared__ float t1s[16];
    gather_rows_v3(hs1, i, offs, csr, idxs, partial);
    __syncthreads();
    float s = 0.f;
#pragma unroll
    for (int q = 0; q < 8; ++q) s += partial[q * 128 + c];
    float x1 = fmaxf(dinv[i] * s + conv1_b[c], 0.f);
    x1s[c] = x1;
    __syncthreads();
    // conv2 matmul with bf16x2-packed weights (k-pairs)
    float h = 0.f;
#pragma unroll 8
    for (int m = 0; m < 64; ++m) {
        unsigned v = w2p[m * 128 + c];
        h += x1s[2 * m] * lo_f(v) + x1s[2 * m + 1] * hi_f(v);
    }
    hs2[(size_t)i * 128 + c] = tob(dinv[i] * h);
    // a1 branch: 128 -> 16 relu -> 16 relu
    if (c < 16) {
        float t = na1_b[c];
#pragma unroll 8
        for (int k = 0; k < 128; ++k) t += x1s[k] * na1_w[k * 16 + c];
        t1s[c] = fmaxf(t, 0.f);
    }
    __syncthreads();
    if (c < 16) {
        float t = na2_b[c];
#pragma unroll
        for (int k = 0; k < 16; ++k) t += t1s[k] * na2_w[k * 16 + c];
        a1[(size_t)i * 16 + c] = fmaxf(t, 0.f);
    }
}

// ---------------- agg2: x2 = relu(agg(hs2)+b2); a2 branch; head f1/f2/f3 -> sigmoid ----------------

__global__ __launch_bounds__(128) void agg2_kernel(
    const bf16* __restrict__ hs2, const int* __restrict__ offs, const int* __restrict__ csr,
    const float* __restrict__ dinv, const float* __restrict__ conv2_b,
    const float* __restrict__ na3_w, const float* __restrict__ na3_b,
    const float* __restrict__ na4_w, const float* __restrict__ na4_b,
    const float* __restrict__ gg, const float* __restrict__ a1,
    const float* __restrict__ f1_w, const float* __restrict__ f1_b,
    const float* __restrict__ f2_w, const float* __restrict__ f2_b,
    const float* __restrict__ f3_w, const float* __restrict__ f3_b,
    float* __restrict__ out, int n) {
    int i = blockIdx.x;
    if (i >= n) return;
    int c = threadIdx.x;
    __shared__ int idxs[128];
    __shared__ float partial[8 * 128];
    __shared__ float x2s[128];
    __shared__ float t1s[16];
    __shared__ float xf[48];
    __shared__ float y1s[64];
    __shared__ float y2s[32];
    gather_rows_v3(hs2, i, offs, csr, idxs, partial);
    __syncthreads();
    float s = 0.f;
#pragma unroll
    for (int q = 0; q < 8; ++q) s += partial[q * 128 + c];
    float x2 = fmaxf(dinv[i] * s + conv2_b[c], 0.f);
    x2s[c] = x2;
    __syncthreads();
    // a2 stage 1 (threads 0..15); threads 32..63 load gg/a1 into xf
    if (c < 16) {
        float t = na3_b[c];
#pragma unroll 8
        for (int k = 0; k < 128; ++k) t += x2s[k] * na3_w[k * 16 + c];
        t1s[c] = fmaxf(t, 0.f);
    } else if (c >= 32 && c < 48) {
        xf[c - 32] = gg[(size_t)i * 16 + (c - 32)];
    } else if (c >= 48 && c < 64) {
        xf[c - 32] = a1[(size_t)i * 16 + (c - 48)];
    }
    __syncthreads();
    if (c < 16) {
        float t = na4_b[c];
#pragma unroll
        for (int k = 0; k < 16; ++k) t += t1s[k] * na4_w[k * 16 + c];
        xf[32 + c] = fmaxf(t, 0.f);
    }
    __syncthreads();
    if (c < 64) {
        float t = f1_b[c];
#pragma unroll 8
        for (int k = 0; k < 48; ++k) t += xf[k] * f1_w[k * 64 + c];
        y1s[c] = fmaxf(t, 0.f);
    }
    __syncthreads();
    if (c < 32) {
        float t = f2_b[c];
#pragma unroll 8
        for (int k = 0; k < 64; ++k) t += y1s[k] * f2_w[k * 32 + c];
        y2s[c] = fmaxf(t, 0.f);
    }
    __syncthreads();
    if (c == 0) {
        float z = f3_b[0];
#pragma unroll
        for (int k = 0; k < 32; ++k) z += y2s[k] * f3_w[k];
        out[i] = 1.f / (1.f + expf(-z));
    }
}

// ---------------- launch ----------------

extern "C" void kernel_launch(void* const* d_in, const int* in_sizes, int n_in,
                              void* d_out, int out_size, void* d_ws, size_t ws_size,
                              hipStream_t stream) {
    const float* x       = (const float*)d_in[0];
    const int*   eidx    = (const int*)d_in[1];
    const float* conv1_w = (const float*)d_in[2];
    const float* conv1_b = (const float*)d_in[3];
    const float* conv2_w = (const float*)d_in[4];
    const float* conv2_b = (const float*)d_in[5];
    const float* ln1_w   = (const float*)d_in[6];
    const float* ln1_b   = (const float*)d_in[7];
    const float* ln2_w   = (const float*)d_in[8];
    const float* ln2_b   = (const float*)d_in[9];
    const float* na1_w   = (const float*)d_in[10];
    const float* na1_b   = (const float*)d_in[11];
    const float* na2_w   = (const float*)d_in[12];
    const float* na2_b   = (const float*)d_in[13];
    const float* na3_w   = (const float*)d_in[14];
    const float* na3_b   = (const float*)d_in[15];
    const float* na4_w   = (const float*)d_in[16];
    const float* na4_b   = (const float*)d_in[17];
    const float* f1_w    = (const float*)d_in[18];
    const float* f1_b    = (const float*)d_in[19];
    const float* f2_w    = (const float*)d_in[20];
    const float* f2_b    = (const float*)d_in[21];
    const float* f3_w    = (const float*)d_in[22];
    const float* f3_b    = (const float*)d_in[23];

    const int N = in_sizes[0] / 16;
    const int E = in_sizes[1] / 2;
    const int NB = (N + SCAN_B - 1) / SCAN_B;

    // workspace carve-up (256B aligned) — ~39 MB
    char* p = (char*)d_ws;
    auto alloc = [&](size_t bytes) {
        char* r = p;
        p += (bytes + 255) & ~(size_t)255;
        return r;
    };
    int*      cnt  = (int*)alloc((size_t)N * 4);          // doubles as scatter cursor
    int*      offs = (int*)alloc(((size_t)N + 1) * 4);
    int*      csr  = (int*)alloc((size_t)E * 4);
    float*    dinv = (float*)alloc((size_t)N * 4);
    int*      flag = (int*)alloc(256);
    int*      part = (int*)alloc((size_t)NB * 4);
    unsigned* w2p  = (unsigned*)alloc((size_t)64 * 128 * 4);
    bf16*     hs1  = (bf16*)alloc((size_t)N * 128 * 2);
    bf16*     hs2  = (bf16*)alloc((size_t)N * 128 * 2);
    float*    ggb  = (float*)alloc((size_t)N * 16 * 4);
    float*    a1b  = (float*)alloc((size_t)N * 16 * 4);

    int eb = (E + 255) / 256;
    hipMemsetAsync(cnt, 0, (size_t)N * 4, stream);
    detect_kernel<<<1, 64, 0, stream>>>(eidx, flag);
    count_kernel<<<eb, 256, 0, stream>>>(eidx, flag, cnt, E, N);
    scan_part_kernel<<<NB, SCAN_B, 0, stream>>>(cnt, offs, part, dinv, N);
    scan_tops_kernel<<<1, 64, 0, stream>>>(part, offs + N, NB);
    scan_apply_kernel<<<NB, SCAN_B, 0, stream>>>(offs, part, N);
    hipMemsetAsync(cnt, 0, (size_t)N * 4, stream);  // reuse as cursor
    scatter_kernel<<<eb, 256, 0, stream>>>(eidx, flag, offs, cnt, csr, E, N);

    pack_w2_kernel<<<32, 256, 0, stream>>>(conv2_w, w2p);
    pre_kernel<<<N, 128, 0, stream>>>(x, conv1_w, ln1_w, ln1_b, ln2_w, ln2_b, dinv, hs1, ggb, N);
    agg1_kernel<<<N, 128, 0, stream>>>(hs1, offs, csr, dinv, conv1_b, w2p,
                                       na1_w, na1_b, na2_w, na2_b, hs2, a1b, N);
    agg2_kernel<<<N, 128, 0, stream>>>(hs2, offs, csr, dinv, conv2_b,
                                       na3_w, na3_b, na4_w, na4_b, ggb, a1b,
                                       f1_w, f1_b, f2_w, f2_b, f3_w, f3_b,
                                       (float*)d_out, N);
}

// Round 7
// 473.703 us; speedup vs baseline: 2.0539x; 1.3110x over previous
//
#include <hip/hip_runtime.h>
#include <hip/hip_bf16.h>

typedef __hip_bfloat16 bf16;
__device__ __forceinline__ float tofb(bf16 v) { return __bfloat162float(v); }
__device__ __forceinline__ bf16 tob(float v) { return __float2bfloat16(v); }
// bf16x2 packed in a uint: low 16 bits = element 2m, high = element 2m+1
__device__ __forceinline__ float lo_f(unsigned v) { return __uint_as_float(v << 16); }
__device__ __forceinline__ float hi_f(unsigned v) { return __uint_as_float(v & 0xffff0000u); }
__device__ __forceinline__ unsigned f2bf_bits(float f) {  // RNE f32->bf16 bits
    unsigned u = __float_as_uint(f);
    return (u + 0x7fffu + ((u >> 16) & 1u)) >> 16;
}

#define SCAN_B 1024

// ---------------- edge-layout probe: int32 (stride 1) vs raw int64 (stride 2) ----------------
__global__ void detect_kernel(const int* __restrict__ e, int* __restrict__ flag) {
    if (threadIdx.x == 0 && blockIdx.x == 0) {
        int s = 0;
        for (int k = 1; k < 64; k += 2) s |= e[k];
        flag[0] = (s == 0) ? 2 : 1;
    }
}

// ---------------- CSR construction ----------------

__global__ __launch_bounds__(256) void count_kernel(const int* __restrict__ eidx,
                                                    const int* __restrict__ flag,
                                                    int* __restrict__ cnt, int E, int n) {
    int stride = flag[0];
    int e = blockIdx.x * 256 + threadIdx.x;
    if (e < E) {
        int d = eidx[(size_t)E * stride + (size_t)e * stride];  // dst row
        if ((unsigned)d < (unsigned)n) atomicAdd(&cnt[d], 1);
    }
}

__global__ __launch_bounds__(SCAN_B) void scan_part_kernel(const int* __restrict__ cnt,
                                                           int* __restrict__ offs,
                                                           int* __restrict__ part,
                                                           float* __restrict__ dinv, int n) {
    __shared__ int s[SCAN_B];
    int i = blockIdx.x * SCAN_B + threadIdx.x;
    int v = (i < n) ? cnt[i] : 0;
    if (i < n) dinv[i] = rsqrtf((float)v + 1.0f);  // +1 self-loop
    s[threadIdx.x] = v;
    __syncthreads();
    for (int off = 1; off < SCAN_B; off <<= 1) {
        int t = (threadIdx.x >= off) ? s[threadIdx.x - off] : 0;
        __syncthreads();
        s[threadIdx.x] += t;
        __syncthreads();
    }
    if (i < n) offs[i] = s[threadIdx.x] - v;  // block-local exclusive
    if (threadIdx.x == SCAN_B - 1) part[blockIdx.x] = s[SCAN_B - 1];
}

__global__ void scan_tops_kernel(int* __restrict__ part, int* __restrict__ offs_n, int nb) {
    if (threadIdx.x == 0 && blockIdx.x == 0) {
        int run = 0;
        for (int b = 0; b < nb; ++b) { int t = part[b]; part[b] = run; run += t; }
        offs_n[0] = run;
    }
}

__global__ __launch_bounds__(SCAN_B) void scan_apply_kernel(int* __restrict__ offs,
                                                            const int* __restrict__ part, int n) {
    int i = blockIdx.x * SCAN_B + threadIdx.x;
    if (i < n) offs[i] += part[blockIdx.x];
}

__global__ __launch_bounds__(256) void scatter_kernel(const int* __restrict__ eidx,
                                                      const int* __restrict__ flag,
                                                      const int* __restrict__ offs,
                                                      int* __restrict__ cursor,
                                                      int* __restrict__ csr, int E, int n) {
    int stride = flag[0];
    int e = blockIdx.x * 256 + threadIdx.x;
    if (e < E) {
        int d = eidx[(size_t)E * stride + (size_t)e * stride];
        int srcv = eidx[(size_t)e * stride];
        if ((unsigned)d < (unsigned)n && (unsigned)srcv < (unsigned)n) {
            int pos = atomicAdd(&cursor[d], 1);
            csr[offs[d] + pos] = srcv;
        }
    }
}

// ---------------- weight pack: conv2_w [128][128] f32 -> bf16x2 pairs over k ----------------
__global__ __launch_bounds__(256) void pack_w2_kernel(const float* __restrict__ w,
                                                      unsigned* __restrict__ wp) {
    int idx = blockIdx.x * 256 + threadIdx.x;
    if (idx < 64 * 128) {
        int m = idx >> 7, c = idx & 127;
        unsigned lo = f2bf_bits(w[(2 * m) * 128 + c]);
        unsigned hi = f2bf_bits(w[(2 * m + 1) * 128 + c]);
        wp[idx] = lo | (hi << 16);
    }
}

// ---------------- pre-pass (16 nodes/block): hs1 = dinv*(x@W1); gg branch ----------------

__global__ __launch_bounds__(256) void pre_kernel(
    const float* __restrict__ x, const float* __restrict__ conv1_w,
    const float* __restrict__ ln1_w, const float* __restrict__ ln1_b,
    const float* __restrict__ ln2_w, const float* __restrict__ ln2_b,
    const float* __restrict__ dinv,
    bf16* __restrict__ hs1, float* __restrict__ gg, int n) {
    int tid = threadIdx.x;
    int i0 = blockIdx.x * 16;
    __shared__ float xls[16 * 20];   // [node][16] pad 20
    __shared__ float tg[16 * 36];    // ln1 out [node][32] pad 36
    {
        int nn = tid >> 4, cc = tid & 15;
        int i = i0 + nn;
        xls[nn * 20 + cc] = (i < n) ? x[(size_t)i * 16 + cc] : 0.f;
    }
    __syncthreads();
    // conv1: thread (c, half) handles 8 nodes (half, half+2, ..., half+14)
    {
        int c = tid & 127, half = tid >> 7;
        float h[8];
#pragma unroll
        for (int r = 0; r < 8; ++r) h[r] = 0.f;
#pragma unroll
        for (int k = 0; k < 16; ++k) {
            float w = conv1_w[k * 128 + c];
#pragma unroll
            for (int r = 0; r < 8; ++r) h[r] += xls[(half + 2 * r) * 20 + k] * w;
        }
#pragma unroll
        for (int r = 0; r < 8; ++r) {
            int i = i0 + half + 2 * r;
            if (i < n) hs1[(size_t)i * 128 + c] = tob(dinv[i] * h[r]);
        }
    }
    // ln1: thread (c in 32, q in 8) handles nodes q, q+8
    {
        int c = tid & 31, q = tid >> 5;
        float t0 = ln1_b[c], t1 = t0;
#pragma unroll
        for (int k = 0; k < 16; ++k) {
            float w = ln1_w[k * 32 + c];
            t0 += xls[q * 20 + k] * w;
            t1 += xls[(q + 8) * 20 + k] * w;
        }
        tg[q * 36 + c] = fmaxf(t0, 0.f);
        tg[(q + 8) * 36 + c] = fmaxf(t1, 0.f);
    }
    __syncthreads();
    // ln2: thread (nn, cc)
    {
        int nn = tid >> 4, cc = tid & 15;
        float t = ln2_b[cc];
#pragma unroll 8
        for (int k = 0; k < 32; ++k) t += tg[nn * 36 + k] * ln2_w[k * 16 + cc];
        int i = i0 + nn;
        if (i < n) gg[(size_t)i * 16 + cc] = fmaxf(t, 0.f);
    }
}

// gather (16 nodes/block): group g (16 lanes) owns node i0+g. Lane sl covers cols sl*8..+7
// (8 f32 accs = complete sums, no cross-lane reduce). Indices via coalesced chunk load +
// __shfl broadcast; unroll 4 -> 4 rows per group in flight (16/wave).
#define ACC8(v)                              \
    a0 += lo_f((v).x); a1 += hi_f((v).x);    \
    a2 += lo_f((v).y); a3 += hi_f((v).y);    \
    a4 += lo_f((v).z); a5 += hi_f((v).z);    \
    a6 += lo_f((v).w); a7 += hi_f((v).w);

#define GATHER16(hs, xs_row_store)                                                   \
    {                                                                                \
        const char* base = (const char*)(hs);                                        \
        int off16 = sl * 16;                                                         \
        float a0 = 0.f, a1 = 0.f, a2 = 0.f, a3 = 0.f,                                \
              a4 = 0.f, a5 = 0.f, a6 = 0.f, a7 = 0.f;                                \
        int e0 = 0, e1 = 0;                                                          \
        if (valid) { e0 = offs[i]; e1 = offs[i + 1]; }                               \
        if (valid) { uint4 v = *(const uint4*)(base + (size_t)i * 256 + off16); ACC8(v) } \
        for (int cb = e0; cb < e1; cb += 16) {                                       \
            int idxv = (cb + sl < e1) ? csr[cb + sl] : 0;                            \
            _Pragma("unroll")                                                        \
            for (int u = 0; u < 4; ++u) {                                            \
                int e = cb + u * 4;                                                  \
                if (e >= e1) break;                                                  \
                int s0 = __shfl(idxv, glane + u * 4 + 0);                            \
                int s1 = __shfl(idxv, glane + u * 4 + 1);                            \
                int s2 = __shfl(idxv, glane + u * 4 + 2);                            \
                int s3 = __shfl(idxv, glane + u * 4 + 3);                            \
                bool m1 = (e + 1 < e1), m2 = (e + 2 < e1), m3 = (e + 3 < e1);        \
                int j1 = m1 ? s1 : i, j2 = m2 ? s2 : i, j3 = m3 ? s3 : i;            \
                uint4 v0 = *(const uint4*)(base + (size_t)s0 * 256 + off16);         \
                uint4 v1 = *(const uint4*)(base + (size_t)j1 * 256 + off16);         \
                uint4 v2 = *(const uint4*)(base + (size_t)j2 * 256 + off16);         \
                uint4 v3 = *(const uint4*)(base + (size_t)j3 * 256 + off16);         \
                ACC8(v0)                                                             \
                if (m1) { ACC8(v1) }                                                 \
                if (m2) { ACC8(v2) }                                                 \
                if (m3) { ACC8(v3) }                                                 \
            }                                                                        \
        }                                                                            \
        xs_row_store                                                                 \
    }

// ---------------- agg1 (16 nodes/block): x1=relu(agg+b1); hs2=dinv*(x1@W2); a1 branch ----------------

__global__ __launch_bounds__(256) void agg1_kernel(
    const bf16* __restrict__ hs1, const int* __restrict__ offs, const int* __restrict__ csr,
    const float* __restrict__ dinv, const float* __restrict__ conv1_b,
    const unsigned* __restrict__ w2p,
    const float* __restrict__ na1_w, const float* __restrict__ na1_b,
    const float* __restrict__ na2_w, const float* __restrict__ na2_b,
    bf16* __restrict__ hs2, float* __restrict__ a1, int n) {
    int tid = threadIdx.x;
    int g = tid >> 4, sl = tid & 15;
    int glane = tid & 48;            // group base lane within wave
    int i0 = blockIdx.x * 16;
    int i = i0 + g;
    bool valid = (i < n);
    __shared__ float xs[16 * 132];   // x1 [node][128] pad 132
    __shared__ float t1s[16 * 20];
    GATHER16(hs1, {
        float* dst = xs + g * 132 + sl * 8;
        if (valid) {
            float di = dinv[i];
            const float* b = conv1_b + sl * 8;
            dst[0] = fmaxf(di * a0 + b[0], 0.f); dst[1] = fmaxf(di * a1 + b[1], 0.f);
            dst[2] = fmaxf(di * a2 + b[2], 0.f); dst[3] = fmaxf(di * a3 + b[3], 0.f);
            dst[4] = fmaxf(di * a4 + b[4], 0.f); dst[5] = fmaxf(di * a5 + b[5], 0.f);
            dst[6] = fmaxf(di * a6 + b[6], 0.f); dst[7] = fmaxf(di * a7 + b[7], 0.f);
        } else {
            dst[0]=dst[1]=dst[2]=dst[3]=dst[4]=dst[5]=dst[6]=dst[7]=0.f;
        }
    })
    __syncthreads();
    // conv2: thread (c, half) handles 8 nodes; weights loaded once, reused 8x
    {
        int c = tid & 127, half = tid >> 7;
        float h[8];
#pragma unroll
        for (int r = 0; r < 8; ++r) h[r] = 0.f;
        for (int m = 0; m < 64; ++m) {
            unsigned w = w2p[m * 128 + c];
            float wl = lo_f(w), wh = hi_f(w);
#pragma unroll
            for (int r = 0; r < 8; ++r) {
                const float* xp = xs + (half + 2 * r) * 132 + 2 * m;
                h[r] += xp[0] * wl + xp[1] * wh;
            }
        }
#pragma unroll
        for (int r = 0; r < 8; ++r) {
            int iN = i0 + half + 2 * r;
            if (iN < n) hs2[(size_t)iN * 128 + c] = tob(dinv[iN] * h[r]);
        }
    }
    // a1 branch: na1 (128->16), na2 (16->16); thread (nn, cc)
    {
        int nn = tid >> 4, cc = tid & 15;
        float t = na1_b[cc];
#pragma unroll 8
        for (int k = 0; k < 128; ++k) t += xs[nn * 132 + k] * na1_w[k * 16 + cc];
        t1s[nn * 20 + cc] = fmaxf(t, 0.f);
        __syncthreads();
        float t2 = na2_b[cc];
#pragma unroll
        for (int k = 0; k < 16; ++k) t2 += t1s[nn * 20 + k] * na2_w[k * 16 + cc];
        int iN = i0 + nn;
        if (iN < n) a1[(size_t)iN * 16 + cc] = fmaxf(t2, 0.f);
    }
}

// ---------------- agg2 (16 nodes/block): x2=relu(agg+b2); a2; head f1/f2/f3 -> sigmoid ----------------

__global__ __launch_bounds__(256) void agg2_kernel(
    const bf16* __restrict__ hs2, const int* __restrict__ offs, const int* __restrict__ csr,
    const float* __restrict__ dinv, const float* __restrict__ conv2_b,
    const float* __restrict__ na3_w, const float* __restrict__ na3_b,
    const float* __restrict__ na4_w, const float* __restrict__ na4_b,
    const float* __restrict__ gg, const float* __restrict__ a1,
    const float* __restrict__ f1_w, const float* __restrict__ f1_b,
    const float* __restrict__ f2_w, const float* __restrict__ f2_b,
    const float* __restrict__ f3_w, const float* __restrict__ f3_b,
    float* __restrict__ out, int n) {
    int tid = threadIdx.x;
    int g = tid >> 4, sl = tid & 15;
    int glane = tid & 48;
    int i0 = blockIdx.x * 16;
    int i = i0 + g;
    bool valid = (i < n);
    __shared__ float xs[16 * 132];   // x2
    __shared__ float t1s[16 * 20];
    __shared__ float xf[16 * 52];    // concat [gg, a1, a2] pad 52
    __shared__ float y1[16 * 68];    // f1 out pad 68
    __shared__ float y2[16 * 36];    // f2 out pad 36
    GATHER16(hs2, {
        float* dst = xs + g * 132 + sl * 8;
        if (valid) {
            float di = dinv[i];
            const float* b = conv2_b + sl * 8;
            dst[0] = fmaxf(di * a0 + b[0], 0.f); dst[1] = fmaxf(di * a1 + b[1], 0.f);
            dst[2] = fmaxf(di * a2 + b[2], 0.f); dst[3] = fmaxf(di * a3 + b[3], 0.f);
            dst[4] = fmaxf(di * a4 + b[4], 0.f); dst[5] = fmaxf(di * a5 + b[5], 0.f);
            dst[6] = fmaxf(di * a6 + b[6], 0.f); dst[7] = fmaxf(di * a7 + b[7], 0.f);
        } else {
            dst[0]=dst[1]=dst[2]=dst[3]=dst[4]=dst[5]=dst[6]=dst[7]=0.f;
        }
    })
    __syncthreads();
    int nn = tid >> 4, cc = tid & 15;
    // stage gg, a1 into xf; compute a2 stage 1 (na3 128->16)
    {
        int iN = i0 + nn;
        bool v = (iN < n);
        size_t ib = (size_t)iN * 16 + cc;
        xf[nn * 52 + cc] = v ? gg[ib] : 0.f;
        xf[nn * 52 + 16 + cc] = v ? a1[ib] : 0.f;
        float t = na3_b[cc];
#pragma unroll 8
        for (int k = 0; k < 128; ++k) t += xs[nn * 132 + k] * na3_w[k * 16 + cc];
        t1s[nn * 20 + cc] = fmaxf(t, 0.f);
    }
    __syncthreads();
    {
        float t2 = na4_b[cc];
#pragma unroll
        for (int k = 0; k < 16; ++k) t2 += t1s[nn * 20 + k] * na4_w[k * 16 + cc];
        xf[nn * 52 + 32 + cc] = fmaxf(t2, 0.f);
    }
    __syncthreads();
    // f1: 48->64; thread (c in 64, q in 4) handles 4 nodes
    {
        int c = tid & 63, q = tid >> 6;
        float y[4];
        float b = f1_b[c];
#pragma unroll
        for (int r = 0; r < 4; ++r) y[r] = b;
#pragma unroll 4
        for (int k = 0; k < 48; ++k) {
            float w = f1_w[k * 64 + c];
#pragma unroll
            for (int r = 0; r < 4; ++r) y[r] += xf[(q + 4 * r) * 52 + k] * w;
        }
#pragma unroll
        for (int r = 0; r < 4; ++r) y1[(q + 4 * r) * 68 + c] = fmaxf(y[r], 0.f);
    }
    __syncthreads();
    // f2: 64->32; thread (c in 32, q in 8) handles 2 nodes
    {
        int c = tid & 31, q = tid >> 5;
        float b = f2_b[c];
        float y0 = b, y8 = b;
#pragma unroll 8
        for (int k = 0; k < 64; ++k) {
            float w = f2_w[k * 32 + c];
            y0 += y1[q * 68 + k] * w;
            y8 += y1[(q + 8) * 68 + k] * w;
        }
        y2[q * 36 + c] = fmaxf(y0, 0.f);
        y2[(q + 8) * 36 + c] = fmaxf(y8, 0.f);
    }
    __syncthreads();
    // f3: 32->1 + sigmoid
    if (tid < 16) {
        float z = f3_b[0];
#pragma unroll
        for (int k = 0; k < 32; ++k) z += y2[tid * 36 + k] * f3_w[k];
        int iN = i0 + tid;
        if (iN < n) out[iN] = 1.f / (1.f + expf(-z));
    }
}

// ---------------- launch ----------------

extern "C" void kernel_launch(void* const* d_in, const int* in_sizes, int n_in,
                              void* d_out, int out_size, void* d_ws, size_t ws_size,
                              hipStream_t stream) {
    const float* x       = (const float*)d_in[0];
    const int*   eidx    = (const int*)d_in[1];
    const float* conv1_w = (const float*)d_in[2];
    const float* conv1_b = (const float*)d_in[3];
    const float* conv2_w = (const float*)d_in[4];
    const float* conv2_b = (const float*)d_in[5];
    const float* ln1_w   = (const float*)d_in[6];
    const float* ln1_b   = (const float*)d_in[7];
    const float* ln2_w   = (const float*)d_in[8];
    const float* ln2_b   = (const float*)d_in[9];
    const float* na1_w   = (const float*)d_in[10];
    const float* na1_b   = (const float*)d_in[11];
    const float* na2_w   = (const float*)d_in[12];
    const float* na2_b   = (const float*)d_in[13];
    const float* na3_w   = (const float*)d_in[14];
    const float* na3_b   = (const float*)d_in[15];
    const float* na4_w   = (const float*)d_in[16];
    const float* na4_b   = (const float*)d_in[17];
    const float* f1_w    = (const float*)d_in[18];
    const float* f1_b    = (const float*)d_in[19];
    const float* f2_w    = (const float*)d_in[20];
    const float* f2_b    = (const float*)d_in[21];
    const float* f3_w    = (const float*)d_in[22];
    const float* f3_b    = (const float*)d_in[23];

    const int N = in_sizes[0] / 16;
    const int E = in_sizes[1] / 2;
    const int NB = (N + SCAN_B - 1) / SCAN_B;
    const int NBLK = (N + 15) / 16;

    // workspace carve-up (256B aligned) — ~39 MB
    char* p = (char*)d_ws;
    auto alloc = [&](size_t bytes) {
        char* r = p;
        p += (bytes + 255) & ~(size_t)255;
        return r;
    };
    int*      cnt  = (int*)alloc((size_t)N * 4);          // doubles as scatter cursor
    int*      offs = (int*)alloc(((size_t)N + 1) * 4);
    int*      csr  = (int*)alloc((size_t)E * 4);
    float*    dinv = (float*)alloc((size_t)N * 4);
    int*      flag = (int*)alloc(256);
    int*      part = (int*)alloc((size_t)NB * 4);
    unsigned* w2p  = (unsigned*)alloc((size_t)64 * 128 * 4);
    bf16*     hs1  = (bf16*)alloc((size_t)N * 128 * 2);
    bf16*     hs2  = (bf16*)alloc((size_t)N * 128 * 2);
    float*    ggb  = (float*)alloc((size_t)N * 16 * 4);
    float*    a1b  = (float*)alloc((size_t)N * 16 * 4);

    int eb = (E + 255) / 256;
    hipMemsetAsync(cnt, 0, (size_t)N * 4, stream);
    detect_kernel<<<1, 64, 0, stream>>>(eidx, flag);
    count_kernel<<<eb, 256, 0, stream>>>(eidx, flag, cnt, E, N);
    scan_part_kernel<<<NB, SCAN_B, 0, stream>>>(cnt, offs, part, dinv, N);
    scan_tops_kernel<<<1, 64, 0, stream>>>(part, offs + N, NB);
    scan_apply_kernel<<<NB, SCAN_B, 0, stream>>>(offs, part, N);
    hipMemsetAsync(cnt, 0, (size_t)N * 4, stream);  // reuse as cursor
    scatter_kernel<<<eb, 256, 0, stream>>>(eidx, flag, offs, cnt, csr, E, N);

    pack_w2_kernel<<<32, 256, 0, stream>>>(conv2_w, w2p);
    pre_kernel<<<NBLK, 256, 0, stream>>>(x, conv1_w, ln1_w, ln1_b, ln2_w, ln2_b, dinv, hs1, ggb, N);
    agg1_kernel<<<NBLK, 256, 0, stream>>>(hs1, offs, csr, dinv, conv1_b, w2p,
                                          na1_w, na1_b, na2_w, na2_b, hs2, a1b, N);
    agg2_kernel<<<NBLK, 256, 0, stream>>>(hs2, offs, csr, dinv, conv2_b,
                                          na3_w, na3_b, na4_w, na4_b, ggb, a1b,
                                          f1_w, f1_b, f2_w, f2_b, f3_w, f3_b,
                                          (float*)d_out, N);
}

// Round 8
// 349.331 us; speedup vs baseline: 2.7852x; 1.3560x over previous
//
#include <hip/hip_runtime.h>
#include <hip/hip_bf16.h>

typedef __hip_bfloat16 bf16;
__device__ __forceinline__ float tofb(bf16 v) { return __bfloat162float(v); }
__device__ __forceinline__ bf16 tob(float v) { return __float2bfloat16(v); }
// bf16x2 packed in a uint: low 16 bits = element 2m, high = element 2m+1
__device__ __forceinline__ float lo_f(unsigned v) { return __uint_as_float(v << 16); }
__device__ __forceinline__ float hi_f(unsigned v) { return __uint_as_float(v & 0xffff0000u); }
__device__ __forceinline__ unsigned f2bf_bits(float f) {  // RNE f32->bf16 bits
    unsigned u = __float_as_uint(f);
    return (u + 0x7fffu + ((u >> 16) & 1u)) >> 16;
}

#define CHUNK 4096   // edges per block in pack/bin

// ---------------- edge-layout probe: int32 (stride 1) vs raw int64 (stride 2) ----------------
__global__ void detect_kernel(const int* __restrict__ e, int* __restrict__ flag) {
    if (threadIdx.x == 0 && blockIdx.x == 0) {
        int s = 0;
        for (int k = 1; k < 64; k += 2) s |= e[k];
        flag[0] = (s == 0) ? 2 : 1;
    }
}

// ---------------- pass A: pack edges to (src<<16)|dst + 256-bucket histogram ----------------
__global__ __launch_bounds__(256) void pack_hist_kernel(const int* __restrict__ eidx,
                                                        const int* __restrict__ flag,
                                                        unsigned* __restrict__ packed,
                                                        int* __restrict__ bhist, int E) {
    __shared__ int h[256];
    int t = threadIdx.x;
    h[t] = 0;
    __syncthreads();
    int stride = flag[0];
    int base = blockIdx.x * CHUNK;
#pragma unroll
    for (int k = 0; k < CHUNK / 256; ++k) {
        int e = base + k * 256 + t;
        if (e < E) {
            unsigned s = (unsigned)eidx[(size_t)e * stride];
            unsigned d = (unsigned)eidx[(size_t)E * stride + (size_t)e * stride];
            packed[e] = (s << 16) | d;
            atomicAdd(&h[d >> 8], 1);
        }
    }
    __syncthreads();
    if (h[t]) atomicAdd(&bhist[t], h[t]);
}

// ---------------- pass B: bucket scan (1 block) -> bases, cursors, offs[N]=E ----------------
__global__ __launch_bounds__(256) void bucket_scan_kernel(const int* __restrict__ bhist,
                                                          int* __restrict__ bbase,
                                                          int* __restrict__ bcur,
                                                          int* __restrict__ offs_n, int E) {
    __shared__ int s[256];
    int t = threadIdx.x;
    int my = bhist[t];
    s[t] = my;
    __syncthreads();
    for (int off = 1; off < 256; off <<= 1) {
        int v = (t >= off) ? s[t - off] : 0;
        __syncthreads();
        s[t] += v;
        __syncthreads();
    }
    int excl = s[t] - my;
    bbase[t] = excl;
    bcur[t] = excl;
    if (t == 0) offs_n[0] = E;
}

// ---------------- pass C: bin edges into bucket-contiguous regions ----------------
__global__ __launch_bounds__(256) void bin_kernel(const unsigned* __restrict__ packed,
                                                  int* __restrict__ bcur,
                                                  unsigned* __restrict__ binned, int E) {
    __shared__ int h[256];
    __shared__ int gbase[256];
    __shared__ int lcur[256];
    int t = threadIdx.x;
    h[t] = 0;
    lcur[t] = 0;
    __syncthreads();
    int base = blockIdx.x * CHUNK;
    unsigned v[CHUNK / 256];
#pragma unroll
    for (int k = 0; k < CHUNK / 256; ++k) {
        int e = base + k * 256 + t;
        v[k] = (e < E) ? packed[e] : 0u;
        if (e < E) atomicAdd(&h[(v[k] & 0xffffu) >> 8], 1);
    }
    __syncthreads();
    int mycnt = h[t];
    if (mycnt) gbase[t] = atomicAdd(&bcur[t], mycnt);
    __syncthreads();
#pragma unroll
    for (int k = 0; k < CHUNK / 256; ++k) {
        int e = base + k * 256 + t;
        if (e < E) {
            int b = (v[k] & 0xffffu) >> 8;
            int r = atomicAdd(&lcur[b], 1);
            binned[gbase[b] + r] = v[k];
        }
    }
}

// ---------------- pass D: per-bucket counting sort -> csr, offs, dinv (no global atomics) ----
__global__ __launch_bounds__(256) void sort_kernel(const unsigned* __restrict__ binned,
                                                   const int* __restrict__ bbase,
                                                   const int* __restrict__ bhist,
                                                   int* __restrict__ offs,
                                                   float* __restrict__ dinv,
                                                   int* __restrict__ csr, int n) {
    __shared__ int lcnt[256];
    __shared__ int lcur[256];
    int b = blockIdx.x, t = threadIdx.x;
    int gstart = bbase[b];
    int bsize = bhist[b];
    lcnt[t] = 0;
    __syncthreads();
    for (int e = t; e < bsize; e += 256) {
        unsigned v = binned[gstart + e];
        atomicAdd(&lcnt[v & 255u], 1);
    }
    __syncthreads();
    int myc = lcnt[t];
    // inclusive scan of lcnt
    for (int off = 1; off < 256; off <<= 1) {
        int x = (t >= off) ? lcnt[t - off] : 0;
        __syncthreads();
        lcnt[t] += x;
        __syncthreads();
    }
    int excl = lcnt[t] - myc;
    int node = (b << 8) + t;
    if (node < n) {
        offs[node] = gstart + excl;
        dinv[node] = rsqrtf((float)myc + 1.0f);  // +1 self-loop
    }
    lcur[t] = excl;
    __syncthreads();
    for (int e = t; e < bsize; e += 256) {
        unsigned v = binned[gstart + e];
        int p = atomicAdd(&lcur[v & 255u], 1);
        csr[gstart + p] = (int)(v >> 16);
    }
}

// ---------------- weight pack: conv2_w [128][128] f32 -> bf16x2 pairs over k ----------------
__global__ __launch_bounds__(256) void pack_w2_kernel(const float* __restrict__ w,
                                                      unsigned* __restrict__ wp) {
    int idx = blockIdx.x * 256 + threadIdx.x;
    if (idx < 64 * 128) {
        int m = idx >> 7, c = idx & 127;
        unsigned lo = f2bf_bits(w[(2 * m) * 128 + c]);
        unsigned hi = f2bf_bits(w[(2 * m + 1) * 128 + c]);
        wp[idx] = lo | (hi << 16);
    }
}

// ---------------- pre-pass (16 nodes/block): hs1 = dinv*(x@W1); gg branch ----------------

__global__ __launch_bounds__(256) void pre_kernel(
    const float* __restrict__ x, const float* __restrict__ conv1_w,
    const float* __restrict__ ln1_w, const float* __restrict__ ln1_b,
    const float* __restrict__ ln2_w, const float* __restrict__ ln2_b,
    const float* __restrict__ dinv,
    bf16* __restrict__ hs1, float* __restrict__ gg, int n) {
    int tid = threadIdx.x;
    int i0 = blockIdx.x * 16;
    __shared__ float xls[16 * 20];   // [node][16] pad 20
    __shared__ float tg[16 * 36];    // ln1 out [node][32] pad 36
    {
        int nn = tid >> 4, cc = tid & 15;
        int i = i0 + nn;
        xls[nn * 20 + cc] = (i < n) ? x[(size_t)i * 16 + cc] : 0.f;
    }
    __syncthreads();
    // conv1: thread (c, half) handles 8 nodes (half, half+2, ..., half+14)
    {
        int c = tid & 127, half = tid >> 7;
        float h[8];
#pragma unroll
        for (int r = 0; r < 8; ++r) h[r] = 0.f;
#pragma unroll
        for (int k = 0; k < 16; ++k) {
            float w = conv1_w[k * 128 + c];
#pragma unroll
            for (int r = 0; r < 8; ++r) h[r] += xls[(half + 2 * r) * 20 + k] * w;
        }
#pragma unroll
        for (int r = 0; r < 8; ++r) {
            int i = i0 + half + 2 * r;
            if (i < n) hs1[(size_t)i * 128 + c] = tob(dinv[i] * h[r]);
        }
    }
    // ln1: thread (c in 32, q in 8) handles nodes q, q+8
    {
        int c = tid & 31, q = tid >> 5;
        float t0 = ln1_b[c], t1 = t0;
#pragma unroll
        for (int k = 0; k < 16; ++k) {
            float w = ln1_w[k * 32 + c];
            t0 += xls[q * 20 + k] * w;
            t1 += xls[(q + 8) * 20 + k] * w;
        }
        tg[q * 36 + c] = fmaxf(t0, 0.f);
        tg[(q + 8) * 36 + c] = fmaxf(t1, 0.f);
    }
    __syncthreads();
    // ln2: thread (nn, cc)
    {
        int nn = tid >> 4, cc = tid & 15;
        float t = ln2_b[cc];
#pragma unroll 8
        for (int k = 0; k < 32; ++k) t += tg[nn * 36 + k] * ln2_w[k * 16 + cc];
        int i = i0 + nn;
        if (i < n) gg[(size_t)i * 16 + cc] = fmaxf(t, 0.f);
    }
}

// gather (16 nodes/block): group g (16 lanes) owns node i0+g. Lane sl covers cols sl*8..+7
// (8 f32 accs = complete sums, no cross-lane reduce). Indices via coalesced chunk load +
// __shfl broadcast; unroll 4 -> 4 rows per group in flight (16/wave).
#define ACC8(v)                              \
    a0 += lo_f((v).x); a1 += hi_f((v).x);    \
    a2 += lo_f((v).y); a3 += hi_f((v).y);    \
    a4 += lo_f((v).z); a5 += hi_f((v).z);    \
    a6 += lo_f((v).w); a7 += hi_f((v).w);

#define GATHER16(hs, xs_row_store)                                                   \
    {                                                                                \
        const char* base = (const char*)(hs);                                        \
        int off16 = sl * 16;                                                         \
        float a0 = 0.f, a1 = 0.f, a2 = 0.f, a3 = 0.f,                                \
              a4 = 0.f, a5 = 0.f, a6 = 0.f, a7 = 0.f;                                \
        int e0 = 0, e1 = 0;                                                          \
        if (valid) { e0 = offs[i]; e1 = offs[i + 1]; }                               \
        if (valid) { uint4 v = *(const uint4*)(base + (size_t)i * 256 + off16); ACC8(v) } \
        for (int cb = e0; cb < e1; cb += 16) {                                       \
            int idxv = (cb + sl < e1) ? csr[cb + sl] : 0;                            \
            _Pragma("unroll")                                                        \
            for (int u = 0; u < 4; ++u) {                                            \
                int e = cb + u * 4;                                                  \
                if (e >= e1) break;                                                  \
                int s0 = __shfl(idxv, glane + u * 4 + 0);                            \
                int s1 = __shfl(idxv, glane + u * 4 + 1);                            \
                int s2 = __shfl(idxv, glane + u * 4 + 2);                            \
                int s3 = __shfl(idxv, glane + u * 4 + 3);                            \
                bool m1 = (e + 1 < e1), m2 = (e + 2 < e1), m3 = (e + 3 < e1);        \
                int j1 = m1 ? s1 : i, j2 = m2 ? s2 : i, j3 = m3 ? s3 : i;            \
                uint4 v0 = *(const uint4*)(base + (size_t)s0 * 256 + off16);         \
                uint4 v1 = *(const uint4*)(base + (size_t)j1 * 256 + off16);         \
                uint4 v2 = *(const uint4*)(base + (size_t)j2 * 256 + off16);         \
                uint4 v3 = *(const uint4*)(base + (size_t)j3 * 256 + off16);         \
                ACC8(v0)                                                             \
                if (m1) { ACC8(v1) }                                                 \
                if (m2) { ACC8(v2) }                                                 \
                if (m3) { ACC8(v3) }                                                 \
            }                                                                        \
        }                                                                            \
        xs_row_store                                                                 \
    }

// ---------------- agg1 (16 nodes/block): x1=relu(agg+b1); hs2=dinv*(x1@W2); a1 branch ----------------

__global__ __launch_bounds__(256) void agg1_kernel(
    const bf16* __restrict__ hs1, const int* __restrict__ offs, const int* __restrict__ csr,
    const float* __restrict__ dinv, const float* __restrict__ conv1_b,
    const unsigned* __restrict__ w2p,
    const float* __restrict__ na1_w, const float* __restrict__ na1_b,
    const float* __restrict__ na2_w, const float* __restrict__ na2_b,
    bf16* __restrict__ hs2, float* __restrict__ a1, int n) {
    int tid = threadIdx.x;
    int g = tid >> 4, sl = tid & 15;
    int glane = tid & 48;            // group base lane within wave
    int i0 = blockIdx.x * 16;
    int i = i0 + g;
    bool valid = (i < n);
    __shared__ float xs[16 * 132];   // x1 [node][128] pad 132
    __shared__ float t1s[16 * 20];
    GATHER16(hs1, {
        float* dst = xs + g * 132 + sl * 8;
        if (valid) {
            float di = dinv[i];
            const float* b = conv1_b + sl * 8;
            dst[0] = fmaxf(di * a0 + b[0], 0.f); dst[1] = fmaxf(di * a1 + b[1], 0.f);
            dst[2] = fmaxf(di * a2 + b[2], 0.f); dst[3] = fmaxf(di * a3 + b[3], 0.f);
            dst[4] = fmaxf(di * a4 + b[4], 0.f); dst[5] = fmaxf(di * a5 + b[5], 0.f);
            dst[6] = fmaxf(di * a6 + b[6], 0.f); dst[7] = fmaxf(di * a7 + b[7], 0.f);
        } else {
            dst[0]=dst[1]=dst[2]=dst[3]=dst[4]=dst[5]=dst[6]=dst[7]=0.f;
        }
    })
    __syncthreads();
    // conv2: thread (c, half) handles 8 nodes; weights loaded once, reused 8x
    {
        int c = tid & 127, half = tid >> 7;
        float h[8];
#pragma unroll
        for (int r = 0; r < 8; ++r) h[r] = 0.f;
        for (int m = 0; m < 64; ++m) {
            unsigned w = w2p[m * 128 + c];
            float wl = lo_f(w), wh = hi_f(w);
#pragma unroll
            for (int r = 0; r < 8; ++r) {
                const float* xp = xs + (half + 2 * r) * 132 + 2 * m;
                h[r] += xp[0] * wl + xp[1] * wh;
            }
        }
#pragma unroll
        for (int r = 0; r < 8; ++r) {
            int iN = i0 + half + 2 * r;
            if (iN < n) hs2[(size_t)iN * 128 + c] = tob(dinv[iN] * h[r]);
        }
    }
    // a1 branch: na1 (128->16), na2 (16->16); thread (nn, cc)
    {
        int nn = tid >> 4, cc = tid & 15;
        float t = na1_b[cc];
#pragma unroll 8
        for (int k = 0; k < 128; ++k) t += xs[nn * 132 + k] * na1_w[k * 16 + cc];
        t1s[nn * 20 + cc] = fmaxf(t, 0.f);
        __syncthreads();
        float t2 = na2_b[cc];
#pragma unroll
        for (int k = 0; k < 16; ++k) t2 += t1s[nn * 20 + k] * na2_w[k * 16 + cc];
        int iN = i0 + nn;
        if (iN < n) a1[(size_t)iN * 16 + cc] = fmaxf(t2, 0.f);
    }
}

// ---------------- agg2 (16 nodes/block): x2=relu(agg+b2); a2; head f1/f2/f3 -> sigmoid ----------------

__global__ __launch_bounds__(256) void agg2_kernel(
    const bf16* __restrict__ hs2, const int* __restrict__ offs, const int* __restrict__ csr,
    const float* __restrict__ dinv, const float* __restrict__ conv2_b,
    const float* __restrict__ na3_w, const float* __restrict__ na3_b,
    const float* __restrict__ na4_w, const float* __restrict__ na4_b,
    const float* __restrict__ gg, const float* __restrict__ a1,
    const float* __restrict__ f1_w, const float* __restrict__ f1_b,
    const float* __restrict__ f2_w, const float* __restrict__ f2_b,
    const float* __restrict__ f3_w, const float* __restrict__ f3_b,
    float* __restrict__ out, int n) {
    int tid = threadIdx.x;
    int g = tid >> 4, sl = tid & 15;
    int glane = tid & 48;
    int i0 = blockIdx.x * 16;
    int i = i0 + g;
    bool valid = (i < n);
    __shared__ float xs[16 * 132];   // x2
    __shared__ float t1s[16 * 20];
    __shared__ float xf[16 * 52];    // concat [gg, a1, a2] pad 52
    __shared__ float y1[16 * 68];    // f1 out pad 68
    __shared__ float y2[16 * 36];    // f2 out pad 36
    GATHER16(hs2, {
        float* dst = xs + g * 132 + sl * 8;
        if (valid) {
            float di = dinv[i];
            const float* b = conv2_b + sl * 8;
            dst[0] = fmaxf(di * a0 + b[0], 0.f); dst[1] = fmaxf(di * a1 + b[1], 0.f);
            dst[2] = fmaxf(di * a2 + b[2], 0.f); dst[3] = fmaxf(di * a3 + b[3], 0.f);
            dst[4] = fmaxf(di * a4 + b[4], 0.f); dst[5] = fmaxf(di * a5 + b[5], 0.f);
            dst[6] = fmaxf(di * a6 + b[6], 0.f); dst[7] = fmaxf(di * a7 + b[7], 0.f);
        } else {
            dst[0]=dst[1]=dst[2]=dst[3]=dst[4]=dst[5]=dst[6]=dst[7]=0.f;
        }
    })
    __syncthreads();
    int nn = tid >> 4, cc = tid & 15;
    // stage gg, a1 into xf; compute a2 stage 1 (na3 128->16)
    {
        int iN = i0 + nn;
        bool v = (iN < n);
        size_t ib = (size_t)iN * 16 + cc;
        xf[nn * 52 + cc] = v ? gg[ib] : 0.f;
        xf[nn * 52 + 16 + cc] = v ? a1[ib] : 0.f;
        float t = na3_b[cc];
#pragma unroll 8
        for (int k = 0; k < 128; ++k) t += xs[nn * 132 + k] * na3_w[k * 16 + cc];
        t1s[nn * 20 + cc] = fmaxf(t, 0.f);
    }
    __syncthreads();
    {
        float t2 = na4_b[cc];
#pragma unroll
        for (int k = 0; k < 16; ++k) t2 += t1s[nn * 20 + k] * na4_w[k * 16 + cc];
        xf[nn * 52 + 32 + cc] = fmaxf(t2, 0.f);
    }
    __syncthreads();
    // f1: 48->64; thread (c in 64, q in 4) handles 4 nodes
    {
        int c = tid & 63, q = tid >> 6;
        float y[4];
        float b = f1_b[c];
#pragma unroll
        for (int r = 0; r < 4; ++r) y[r] = b;
#pragma unroll 4
        for (int k = 0; k < 48; ++k) {
            float w = f1_w[k * 64 + c];
#pragma unroll
            for (int r = 0; r < 4; ++r) y[r] += xf[(q + 4 * r) * 52 + k] * w;
        }
#pragma unroll
        for (int r = 0; r < 4; ++r) y1[(q + 4 * r) * 68 + c] = fmaxf(y[r], 0.f);
    }
    __syncthreads();
    // f2: 64->32; thread (c in 32, q in 8) handles 2 nodes
    {
        int c = tid & 31, q = tid >> 5;
        float b = f2_b[c];
        float y0 = b, y8 = b;
#pragma unroll 8
        for (int k = 0; k < 64; ++k) {
            float w = f2_w[k * 32 + c];
            y0 += y1[q * 68 + k] * w;
            y8 += y1[(q + 8) * 68 + k] * w;
        }
        y2[q * 36 + c] = fmaxf(y0, 0.f);
        y2[(q + 8) * 36 + c] = fmaxf(y8, 0.f);
    }
    __syncthreads();
    // f3: 32->1 + sigmoid
    if (tid < 16) {
        float z = f3_b[0];
#pragma unroll
        for (int k = 0; k < 32; ++k) z += y2[tid * 36 + k] * f3_w[k];
        int iN = i0 + tid;
        if (iN < n) out[iN] = 1.f / (1.f + expf(-z));
    }
}

// ---------------- launch ----------------

extern "C" void kernel_launch(void* const* d_in, const int* in_sizes, int n_in,
                              void* d_out, int out_size, void* d_ws, size_t ws_size,
                              hipStream_t stream) {
    const float* x       = (const float*)d_in[0];
    const int*   eidx    = (const int*)d_in[1];
    const float* conv1_w = (const float*)d_in[2];
    const float* conv1_b = (const float*)d_in[3];
    const float* conv2_w = (const float*)d_in[4];
    const float* conv2_b = (const float*)d_in[5];
    const float* ln1_w   = (const float*)d_in[6];
    const float* ln1_b   = (const float*)d_in[7];
    const float* ln2_w   = (const float*)d_in[8];
    const float* ln2_b   = (const float*)d_in[9];
    const float* na1_w   = (const float*)d_in[10];
    const float* na1_b   = (const float*)d_in[11];
    const float* na2_w   = (const float*)d_in[12];
    const float* na2_b   = (const float*)d_in[13];
    const float* na3_w   = (const float*)d_in[14];
    const float* na3_b   = (const float*)d_in[15];
    const float* na4_w   = (const float*)d_in[16];
    const float* na4_b   = (const float*)d_in[17];
    const float* f1_w    = (const float*)d_in[18];
    const float* f1_b    = (const float*)d_in[19];
    const float* f2_w    = (const float*)d_in[20];
    const float* f2_b    = (const float*)d_in[21];
    const float* f3_w    = (const float*)d_in[22];
    const float* f3_b    = (const float*)d_in[23];

    const int N = in_sizes[0] / 16;          // 50000 (< 65536: 16-bit packing valid)
    const int E = in_sizes[1] / 2;
    const int NBUCK = (N + 255) >> 8;
    const int EB = (E + CHUNK - 1) / CHUNK;
    const int NBLK = (N + 15) / 16;

    // workspace carve-up (256B aligned) — ~45 MB
    char* p = (char*)d_ws;
    auto alloc = [&](size_t bytes) {
        char* r = p;
        p += (bytes + 255) & ~(size_t)255;
        return r;
    };
    int*      bhist  = (int*)alloc(256 * 4);
    int*      bbase  = (int*)alloc(256 * 4);
    int*      bcur   = (int*)alloc(256 * 4);
    int*      flag   = (int*)alloc(256);
    int*      offs   = (int*)alloc(((size_t)N + 1) * 4);
    unsigned* packed = (unsigned*)alloc((size_t)E * 4);   // later reused as csr
    unsigned* binned = (unsigned*)alloc((size_t)E * 4);
    float*    dinv   = (float*)alloc((size_t)N * 4);
    unsigned* w2p    = (unsigned*)alloc((size_t)64 * 128 * 4);
    bf16*     hs1    = (bf16*)alloc((size_t)N * 128 * 2);
    bf16*     hs2    = (bf16*)alloc((size_t)N * 128 * 2);
    float*    ggb    = (float*)alloc((size_t)N * 16 * 4);
    float*    a1b    = (float*)alloc((size_t)N * 16 * 4);
    int*      csr    = (int*)packed;  // alias: packed dead after bin_kernel

    hipMemsetAsync(bhist, 0, 256 * 4, stream);
    detect_kernel<<<1, 64, 0, stream>>>(eidx, flag);
    pack_hist_kernel<<<EB, 256, 0, stream>>>(eidx, flag, packed, bhist, E);
    bucket_scan_kernel<<<1, 256, 0, stream>>>(bhist, bbase, bcur, offs + N, E);
    bin_kernel<<<EB, 256, 0, stream>>>(packed, bcur, binned, E);
    sort_kernel<<<NBUCK, 256, 0, stream>>>(binned, bbase, bhist, offs, dinv, csr, N);

    pack_w2_kernel<<<32, 256, 0, stream>>>(conv2_w, w2p);
    pre_kernel<<<NBLK, 256, 0, stream>>>(x, conv1_w, ln1_w, ln1_b, ln2_w, ln2_b, dinv, hs1, ggb, N);
    agg1_kernel<<<NBLK, 256, 0, stream>>>(hs1, offs, csr, dinv, conv1_b, w2p,
                                          na1_w, na1_b, na2_w, na2_b, hs2, a1b, N);
    agg2_kernel<<<NBLK, 256, 0, stream>>>(hs2, offs, csr, dinv, conv2_b,
                                          na3_w, na3_b, na4_w, na4_b, ggb, a1b,
                                          f1_w, f1_b, f2_w, f2_b, f3_w, f3_b,
                                          (float*)d_out, N);
}

// Round 10
// 330.396 us; speedup vs baseline: 2.9448x; 1.0573x over previous
//
#include <hip/hip_runtime.h>
#include <hip/hip_bf16.h>

typedef __hip_bfloat16 bf16;
typedef __attribute__((ext_vector_type(8))) short short8;
typedef __attribute__((ext_vector_type(4))) float f32x4;

__device__ __forceinline__ float tofb(bf16 v) { return __bfloat162float(v); }
__device__ __forceinline__ bf16 tob(float v) { return __float2bfloat16(v); }
// bf16x2 packed in a uint: low 16 bits = element 2m, high = element 2m+1
__device__ __forceinline__ float lo_f(unsigned v) { return __uint_as_float(v << 16); }
__device__ __forceinline__ float hi_f(unsigned v) { return __uint_as_float(v & 0xffff0000u); }
__device__ __forceinline__ unsigned f2bf_bits(float f) {  // RNE f32->bf16 bits
    unsigned u = __float_as_uint(f);
    return (u + 0x7fffu + ((u >> 16) & 1u)) >> 16;
}

#define CHUNK 4096   // edges per block in pack/bin

// ---------------- pass A: pack edges to (src<<16)|dst + 256-bucket histogram ----------------
// (edge layout probed in-block: odd int32 slots all zero => raw int64, stride 2)
__global__ __launch_bounds__(256) void pack_hist_kernel(const int* __restrict__ eidx,
                                                        unsigned* __restrict__ packed,
                                                        int* __restrict__ bhist, int E) {
    __shared__ int h[256];
    __shared__ int sodd;
    int t = threadIdx.x;
    h[t] = 0;
    if (t == 0) sodd = 0;
    __syncthreads();
    if (t < 32) atomicOr(&sodd, eidx[2 * t + 1]);
    __syncthreads();
    int stride = (sodd == 0) ? 2 : 1;
    int base = blockIdx.x * CHUNK;
#pragma unroll
    for (int k = 0; k < CHUNK / 256; ++k) {
        int e = base + k * 256 + t;
        if (e < E) {
            unsigned s = (unsigned)eidx[(size_t)e * stride];
            unsigned d = (unsigned)eidx[(size_t)E * stride + (size_t)e * stride];
            packed[e] = (s << 16) | d;
            atomicAdd(&h[d >> 8], 1);
        }
    }
    __syncthreads();
    if (h[t]) atomicAdd(&bhist[t], h[t]);
}

// ---------------- pass B: bucket scan (1 block) -> bases, cursors, offs[N]=E ----------------
__global__ __launch_bounds__(256) void bucket_scan_kernel(const int* __restrict__ bhist,
                                                          int* __restrict__ bbase,
                                                          int* __restrict__ bcur,
                                                          int* __restrict__ offs_n, int E) {
    __shared__ int s[256];
    int t = threadIdx.x;
    int my = bhist[t];
    s[t] = my;
    __syncthreads();
    for (int off = 1; off < 256; off <<= 1) {
        int v = (t >= off) ? s[t - off] : 0;
        __syncthreads();
        s[t] += v;
        __syncthreads();
    }
    int excl = s[t] - my;
    bbase[t] = excl;
    bcur[t] = excl;
    if (t == 0) offs_n[0] = E;
}

// ---------------- pass C: bin edges into bucket-contiguous regions ----------------
__global__ __launch_bounds__(256) void bin_kernel(const unsigned* __restrict__ packed,
                                                  int* __restrict__ bcur,
                                                  unsigned* __restrict__ binned, int E) {
    __shared__ int h[256];
    __shared__ int gbase[256];
    __shared__ int lcur[256];
    int t = threadIdx.x;
    h[t] = 0;
    lcur[t] = 0;
    __syncthreads();
    int base = blockIdx.x * CHUNK;
    unsigned v[CHUNK / 256];
#pragma unroll
    for (int k = 0; k < CHUNK / 256; ++k) {
        int e = base + k * 256 + t;
        v[k] = (e < E) ? packed[e] : 0u;
        if (e < E) atomicAdd(&h[(v[k] & 0xffffu) >> 8], 1);
    }
    __syncthreads();
    int mycnt = h[t];
    if (mycnt) gbase[t] = atomicAdd(&bcur[t], mycnt);
    __syncthreads();
#pragma unroll
    for (int k = 0; k < CHUNK / 256; ++k) {
        int e = base + k * 256 + t;
        if (e < E) {
            int b = (v[k] & 0xffffu) >> 8;
            int r = atomicAdd(&lcur[b], 1);
            binned[gbase[b] + r] = v[k];
        }
    }
}

// ---------------- pass D: per-bucket counting sort -> csr, offs, dinv (no global atomics) ----
__global__ __launch_bounds__(256) void sort_kernel(const unsigned* __restrict__ binned,
                                                   const int* __restrict__ bbase,
                                                   const int* __restrict__ bhist,
                                                   int* __restrict__ offs,
                                                   float* __restrict__ dinv,
                                                   int* __restrict__ csr, int n) {
    __shared__ int lcnt[256];
    __shared__ int lcur[256];
    int b = blockIdx.x, t = threadIdx.x;
    int gstart = bbase[b];
    int bsize = bhist[b];
    lcnt[t] = 0;
    __syncthreads();
    for (int e = t; e < bsize; e += 256) {
        unsigned v = binned[gstart + e];
        atomicAdd(&lcnt[v & 255u], 1);
    }
    __syncthreads();
    int myc = lcnt[t];
    for (int off = 1; off < 256; off <<= 1) {
        int x = (t >= off) ? lcnt[t - off] : 0;
        __syncthreads();
        lcnt[t] += x;
        __syncthreads();
    }
    int excl = lcnt[t] - myc;
    int node = (b << 8) + t;
    if (node < n) {
        offs[node] = gstart + excl;
        dinv[node] = rsqrtf((float)myc + 1.0f);  // +1 self-loop
    }
    lcur[t] = excl;
    __syncthreads();
    for (int e = t; e < bsize; e += 256) {
        unsigned v = binned[gstart + e];
        int p = atomicAdd(&lcur[v & 255u], 1);
        csr[gstart + p] = (int)(v >> 16);
    }
}

// ---------------- weight pack: conv2_w -> MFMA B-fragment order (bf16) ----------------
// w2f[((t*4 + s)*64 + lane)*8 + j] = bf16(w2[k=s*32+(lane>>4)*8+j][n=t*16+(lane&15)])
__global__ __launch_bounds__(256) void pack_w2_frag_kernel(const float* __restrict__ w,
                                                           unsigned short* __restrict__ wf) {
    int idx = blockIdx.x * 256 + threadIdx.x;   // 0 .. 16383
    if (idx < 8 * 4 * 64 * 8) {
        int j = idx & 7;
        int lane = (idx >> 3) & 63;
        int s = (idx >> 9) & 3;
        int t = idx >> 11;
        int k = s * 32 + ((lane >> 4) << 3) + j;
        int nn = t * 16 + (lane & 15);
        wf[idx] = (unsigned short)f2bf_bits(w[k * 128 + nn]);
    }
}

// ---------------- pre-pass (16 nodes/block): hs1 = dinv*(x@W1); gg branch ----------------

__global__ __launch_bounds__(256) void pre_kernel(
    const float* __restrict__ x, const float* __restrict__ conv1_w,
    const float* __restrict__ ln1_w, const float* __restrict__ ln1_b,
    const float* __restrict__ ln2_w, const float* __restrict__ ln2_b,
    const float* __restrict__ dinv,
    bf16* __restrict__ hs1, float* __restrict__ gg, int n) {
    int tid = threadIdx.x;
    int i0 = blockIdx.x * 16;
    __shared__ float xls[16 * 20];   // [node][16] pad 20
    __shared__ float tg[16 * 36];    // ln1 out [node][32] pad 36
    {
        int nn = tid >> 4, cc = tid & 15;
        int i = i0 + nn;
        xls[nn * 20 + cc] = (i < n) ? x[(size_t)i * 16 + cc] : 0.f;
    }
    __syncthreads();
    {
        int c = tid & 127, half = tid >> 7;
        float h[8];
#pragma unroll
        for (int r = 0; r < 8; ++r) h[r] = 0.f;
#pragma unroll
        for (int k = 0; k < 16; ++k) {
            float w = conv1_w[k * 128 + c];
#pragma unroll
            for (int r = 0; r < 8; ++r) h[r] += xls[(half + 2 * r) * 20 + k] * w;
        }
#pragma unroll
        for (int r = 0; r < 8; ++r) {
            int i = i0 + half + 2 * r;
            if (i < n) hs1[(size_t)i * 128 + c] = tob(dinv[i] * h[r]);
        }
    }
    {
        int c = tid & 31, q = tid >> 5;
        float t0 = ln1_b[c], t1 = t0;
#pragma unroll
        for (int k = 0; k < 16; ++k) {
            float w = ln1_w[k * 32 + c];
            t0 += xls[q * 20 + k] * w;
            t1 += xls[(q + 8) * 20 + k] * w;
        }
        tg[q * 36 + c] = fmaxf(t0, 0.f);
        tg[(q + 8) * 36 + c] = fmaxf(t1, 0.f);
    }
    __syncthreads();
    {
        int nn = tid >> 4, cc = tid & 15;
        float t = ln2_b[cc];
#pragma unroll 8
        for (int k = 0; k < 32; ++k) t += tg[nn * 36 + k] * ln2_w[k * 16 + cc];
        int i = i0 + nn;
        if (i < n) gg[(size_t)i * 16 + cc] = fmaxf(t, 0.f);
    }
}

// gather (16 nodes/block): group g (16 lanes) owns node i0+g. Lane sl covers cols sl*8..+7.
// NOTE: variadic macro — the epilogue block may contain top-level commas.
#define ACC8(v)                              \
    a0 += lo_f((v).x); a1 += hi_f((v).x);    \
    a2 += lo_f((v).y); a3 += hi_f((v).y);    \
    a4 += lo_f((v).z); a5 += hi_f((v).z);    \
    a6 += lo_f((v).w); a7 += hi_f((v).w);

#define GATHER16(hs, ...)                                                            \
    {                                                                                \
        const char* base = (const char*)(hs);                                        \
        int off16 = sl * 16;                                                         \
        float a0 = 0.f, a1 = 0.f, a2 = 0.f, a3 = 0.f,                                \
              a4 = 0.f, a5 = 0.f, a6 = 0.f, a7 = 0.f;                                \
        int e0 = 0, e1 = 0;                                                          \
        if (valid) { e0 = offs[i]; e1 = offs[i + 1]; }                               \
        if (valid) { uint4 v = *(const uint4*)(base + (size_t)i * 256 + off16); ACC8(v) } \
        for (int cb = e0; cb < e1; cb += 16) {                                       \
            int idxv = (cb + sl < e1) ? csr[cb + sl] : 0;                            \
            _Pragma("unroll")                                                        \
            for (int u = 0; u < 4; ++u) {                                            \
                int e = cb + u * 4;                                                  \
                if (e >= e1) break;                                                  \
                int s0 = __shfl(idxv, glane + u * 4 + 0);                            \
                int s1 = __shfl(idxv, glane + u * 4 + 1);                            \
                int s2 = __shfl(idxv, glane + u * 4 + 2);                            \
                int s3 = __shfl(idxv, glane + u * 4 + 3);                            \
                bool m1 = (e + 1 < e1), m2 = (e + 2 < e1), m3 = (e + 3 < e1);        \
                int j1 = m1 ? s1 : i, j2 = m2 ? s2 : i, j3 = m3 ? s3 : i;            \
                uint4 v0 = *(const uint4*)(base + (size_t)s0 * 256 + off16);         \
                uint4 v1 = *(const uint4*)(base + (size_t)j1 * 256 + off16);         \
                uint4 v2 = *(const uint4*)(base + (size_t)j2 * 256 + off16);         \
                uint4 v3 = *(const uint4*)(base + (size_t)j3 * 256 + off16);         \
                ACC8(v0)                                                             \
                if (m1) { ACC8(v1) }                                                 \
                if (m2) { ACC8(v2) }                                                 \
                if (m3) { ACC8(v3) }                                                 \
            }                                                                        \
        }                                                                            \
        __VA_ARGS__                                                                  \
    }

// ---------------- agg1 (16 nodes/block): x1=relu(agg+b1); hs2=dinv*(x1@W2) via MFMA; a1 ----

__global__ __launch_bounds__(256) void agg1_kernel(
    const bf16* __restrict__ hs1, const int* __restrict__ offs, const int* __restrict__ csr,
    const float* __restrict__ dinv, const float* __restrict__ conv1_b,
    const unsigned short* __restrict__ w2f,
    const float* __restrict__ na1_w, const float* __restrict__ na1_b,
    const float* __restrict__ na2_w, const float* __restrict__ na2_b,
    bf16* __restrict__ hs2, float* __restrict__ a1, int n) {
    int tid = threadIdx.x;
    int g = tid >> 4, sl = tid & 15;
    int glane = tid & 48;            // group base lane within wave
    int i0 = blockIdx.x * 16;
    int i = i0 + g;
    bool valid = (i < n);
    // x1 as bf16, row stride 136 elems (272 B = 17*16B: frag reads 2-way aliased = free)
    __shared__ short xsb[16 * 136];
    __shared__ float t1s[16 * 20];
    GATHER16(hs1, {
        float r0 = 0.f; float r1 = 0.f; float r2 = 0.f; float r3 = 0.f;
        float r4 = 0.f; float r5 = 0.f; float r6 = 0.f; float r7 = 0.f;
        if (valid) {
            float di = dinv[i];
            const float* b = conv1_b + sl * 8;
            r0 = fmaxf(di * a0 + b[0], 0.f); r1 = fmaxf(di * a1 + b[1], 0.f);
            r2 = fmaxf(di * a2 + b[2], 0.f); r3 = fmaxf(di * a3 + b[3], 0.f);
            r4 = fmaxf(di * a4 + b[4], 0.f); r5 = fmaxf(di * a5 + b[5], 0.f);
            r6 = fmaxf(di * a6 + b[6], 0.f); r7 = fmaxf(di * a7 + b[7], 0.f);
        }
        uint4 pk;
        pk.x = f2bf_bits(r0) | (f2bf_bits(r1) << 16);
        pk.y = f2bf_bits(r2) | (f2bf_bits(r3) << 16);
        pk.z = f2bf_bits(r4) | (f2bf_bits(r5) << 16);
        pk.w = f2bf_bits(r6) | (f2bf_bits(r7) << 16);
        *(uint4*)((char*)xsb + g * 272 + sl * 16) = pk;
    })
    __syncthreads();
    // conv2 via MFMA: D[16 nodes][128 cols]; wave w covers col-tiles 2w, 2w+1
    {
        int lane = tid & 63;
        int wv = tid >> 6;
        int quad = lane >> 4;
        int lm = lane & 15;
        int t0 = wv * 2;
        f32x4 acc0 = {0.f, 0.f, 0.f, 0.f};
        f32x4 acc1 = {0.f, 0.f, 0.f, 0.f};
        const short8* wf = (const short8*)w2f;
#pragma unroll
        for (int s = 0; s < 4; ++s) {
            short8 a = *(const short8*)((const char*)xsb + lm * 272 + s * 64 + quad * 16);
            short8 b0 = wf[(t0 * 4 + s) * 64 + lane];
            short8 b1 = wf[((t0 + 1) * 4 + s) * 64 + lane];
            acc0 = __builtin_amdgcn_mfma_f32_16x16x32_bf16(a, b0, acc0, 0, 0, 0);
            acc1 = __builtin_amdgcn_mfma_f32_16x16x32_bf16(a, b1, acc1, 0, 0, 0);
        }
#pragma unroll
        for (int r = 0; r < 4; ++r) {
            int iN = i0 + quad * 4 + r;     // C/D: row = quad*4+reg, col = lane&15
            if (iN < n) {
                float di = dinv[iN];
                hs2[(size_t)iN * 128 + t0 * 16 + lm] = tob(di * acc0[r]);
                hs2[(size_t)iN * 128 + (t0 + 1) * 16 + lm] = tob(di * acc1[r]);
            }
        }
    }
    // a1 branch: na1 (128->16) from bf16 x1, na2 (16->16)
    {
        int nn = tid >> 4;
        int cc = tid & 15;
        const bf16* xrow = (const bf16*)((const char*)xsb + nn * 272);
        float t = na1_b[cc];
#pragma unroll 8
        for (int k = 0; k < 128; ++k) t += tofb(xrow[k]) * na1_w[k * 16 + cc];
        t1s[nn * 20 + cc] = fmaxf(t, 0.f);
        __syncthreads();
        float t2 = na2_b[cc];
#pragma unroll
        for (int k = 0; k < 16; ++k) t2 += t1s[nn * 20 + k] * na2_w[k * 16 + cc];
        int iN = i0 + nn;
        if (iN < n) a1[(size_t)iN * 16 + cc] = fmaxf(t2, 0.f);
    }
}

// ---------------- agg2 (16 nodes/block): x2=relu(agg+b2); a2; head f1/f2/f3 -> sigmoid ----------------

__global__ __launch_bounds__(256) void agg2_kernel(
    const bf16* __restrict__ hs2, const int* __restrict__ offs, const int* __restrict__ csr,
    const float* __restrict__ dinv, const float* __restrict__ conv2_b,
    const float* __restrict__ na3_w, const float* __restrict__ na3_b,
    const float* __restrict__ na4_w, const float* __restrict__ na4_b,
    const float* __restrict__ gg, const float* __restrict__ a1,
    const float* __restrict__ f1_w, const float* __restrict__ f1_b,
    const float* __restrict__ f2_w, const float* __restrict__ f2_b,
    const float* __restrict__ f3_w, const float* __restrict__ f3_b,
    float* __restrict__ out, int n) {
    int tid = threadIdx.x;
    int g = tid >> 4, sl = tid & 15;
    int glane = tid & 48;
    int i0 = blockIdx.x * 16;
    int i = i0 + g;
    bool valid = (i < n);
    __shared__ float xs[16 * 132];   // x2
    __shared__ float t1s[16 * 20];
    __shared__ float xf[16 * 52];    // concat [gg, a1, a2] pad 52
    __shared__ float y1[16 * 68];    // f1 out pad 68
    __shared__ float y2[16 * 36];    // f2 out pad 36
    GATHER16(hs2, {
        float* dst = xs + g * 132 + sl * 8;
        if (valid) {
            float di = dinv[i];
            const float* b = conv2_b + sl * 8;
            dst[0] = fmaxf(di * a0 + b[0], 0.f); dst[1] = fmaxf(di * a1 + b[1], 0.f);
            dst[2] = fmaxf(di * a2 + b[2], 0.f); dst[3] = fmaxf(di * a3 + b[3], 0.f);
            dst[4] = fmaxf(di * a4 + b[4], 0.f); dst[5] = fmaxf(di * a5 + b[5], 0.f);
            dst[6] = fmaxf(di * a6 + b[6], 0.f); dst[7] = fmaxf(di * a7 + b[7], 0.f);
        } else {
            dst[0]=dst[1]=dst[2]=dst[3]=dst[4]=dst[5]=dst[6]=dst[7]=0.f;
        }
    })
    __syncthreads();
    int nn = tid >> 4, cc = tid & 15;
    {
        int iN = i0 + nn;
        bool v = (iN < n);
        size_t ib = (size_t)iN * 16 + cc;
        xf[nn * 52 + cc] = v ? gg[ib] : 0.f;
        xf[nn * 52 + 16 + cc] = v ? a1[ib] : 0.f;
        float t = na3_b[cc];
#pragma unroll 8
        for (int k = 0; k < 128; ++k) t += xs[nn * 132 + k] * na3_w[k * 16 + cc];
        t1s[nn * 20 + cc] = fmaxf(t, 0.f);
    }
    __syncthreads();
    {
        float t2 = na4_b[cc];
#pragma unroll
        for (int k = 0; k < 16; ++k) t2 += t1s[nn * 20 + k] * na4_w[k * 16 + cc];
        xf[nn * 52 + 32 + cc] = fmaxf(t2, 0.f);
    }
    __syncthreads();
    {
        int c = tid & 63, q = tid >> 6;
        float y[4];
        float b = f1_b[c];
#pragma unroll
        for (int r = 0; r < 4; ++r) y[r] = b;
#pragma unroll 4
        for (int k = 0; k < 48; ++k) {
            float w = f1_w[k * 64 + c];
#pragma unroll
            for (int r = 0; r < 4; ++r) y[r] += xf[(q + 4 * r) * 52 + k] * w;
        }
#pragma unroll
        for (int r = 0; r < 4; ++r) y1[(q + 4 * r) * 68 + c] = fmaxf(y[r], 0.f);
    }
    __syncthreads();
    {
        int c = tid & 31, q = tid >> 5;
        float b = f2_b[c];
        float y0 = b, y8 = b;
#pragma unroll 8
        for (int k = 0; k < 64; ++k) {
            float w = f2_w[k * 32 + c];
            y0 += y1[q * 68 + k] * w;
            y8 += y1[(q + 8) * 68 + k] * w;
        }
        y2[q * 36 + c] = fmaxf(y0, 0.f);
        y2[(q + 8) * 36 + c] = fmaxf(y8, 0.f);
    }
    __syncthreads();
    if (tid < 16) {
        float z = f3_b[0];
#pragma unroll
        for (int k = 0; k < 32; ++k) z += y2[tid * 36 + k] * f3_w[k];
        int iN = i0 + tid;
        if (iN < n) out[iN] = 1.f / (1.f + expf(-z));
    }
}

// ---------------- launch ----------------

extern "C" void kernel_launch(void* const* d_in, const int* in_sizes, int n_in,
                              void* d_out, int out_size, void* d_ws, size_t ws_size,
                              hipStream_t stream) {
    const float* x       = (const float*)d_in[0];
    const int*   eidx    = (const int*)d_in[1];
    const float* conv1_w = (const float*)d_in[2];
    const float* conv1_b = (const float*)d_in[3];
    const float* conv2_w = (const float*)d_in[4];
    const float* conv2_b = (const float*)d_in[5];
    const float* ln1_w   = (const float*)d_in[6];
    const float* ln1_b   = (const float*)d_in[7];
    const float* ln2_w   = (const float*)d_in[8];
    const float* ln2_b   = (const float*)d_in[9];
    const float* na1_w   = (const float*)d_in[10];
    const float* na1_b   = (const float*)d_in[11];
    const float* na2_w   = (const float*)d_in[12];
    const float* na2_b   = (const float*)d_in[13];
    const float* na3_w   = (const float*)d_in[14];
    const float* na3_b   = (const float*)d_in[15];
    const float* na4_w   = (const float*)d_in[16];
    const float* na4_b   = (const float*)d_in[17];
    const float* f1_w    = (const float*)d_in[18];
    const float* f1_b    = (const float*)d_in[19];
    const float* f2_w    = (const float*)d_in[20];
    const float* f2_b    = (const float*)d_in[21];
    const float* f3_w    = (const float*)d_in[22];
    const float* f3_b    = (const float*)d_in[23];

    const int N = in_sizes[0] / 16;          // 50000 (< 65536: 16-bit packing valid)
    const int E = in_sizes[1] / 2;
    const int NBUCK = (N + 255) >> 8;
    const int EB = (E + CHUNK - 1) / CHUNK;
    const int NBLK = (N + 15) / 16;

    // workspace carve-up (256B aligned) — ~45 MB
    char* p = (char*)d_ws;
    auto alloc = [&](size_t bytes) {
        char* r = p;
        p += (bytes + 255) & ~(size_t)255;
        return r;
    };
    int*            bhist  = (int*)alloc(256 * 4);
    int*            bbase  = (int*)alloc(256 * 4);
    int*            bcur   = (int*)alloc(256 * 4);
    int*            offs   = (int*)alloc(((size_t)N + 1) * 4);
    unsigned*       packed = (unsigned*)alloc((size_t)E * 4);   // later reused as csr
    unsigned*       binned = (unsigned*)alloc((size_t)E * 4);
    float*          dinv   = (float*)alloc((size_t)N * 4);
    unsigned short* w2f    = (unsigned short*)alloc((size_t)8 * 4 * 64 * 8 * 2);
    bf16*           hs1    = (bf16*)alloc((size_t)N * 128 * 2);
    bf16*           hs2    = (bf16*)alloc((size_t)N * 128 * 2);
    float*          ggb    = (float*)alloc((size_t)N * 16 * 4);
    float*          a1b    = (float*)alloc((size_t)N * 16 * 4);
    int*            csr    = (int*)packed;  // alias: packed dead after bin_kernel

    hipMemsetAsync(bhist, 0, 256 * 4, stream);
    pack_hist_kernel<<<EB, 256, 0, stream>>>(eidx, packed, bhist, E);
    bucket_scan_kernel<<<1, 256, 0, stream>>>(bhist, bbase, bcur, offs + N, E);
    bin_kernel<<<EB, 256, 0, stream>>>(packed, bcur, binned, E);
    sort_kernel<<<NBUCK, 256, 0, stream>>>(binned, bbase, bhist, offs, dinv, csr, N);

    pack_w2_frag_kernel<<<64, 256, 0, stream>>>(conv2_w, w2f);
    pre_kernel<<<NBLK, 256, 0, stream>>>(x, conv1_w, ln1_w, ln1_b, ln2_w, ln2_b, dinv, hs1, ggb, N);
    agg1_kernel<<<NBLK, 256, 0, stream>>>(hs1, offs, csr, dinv, conv1_b, w2f,
                                          na1_w, na1_b, na2_w, na2_b, hs2, a1b, N);
    agg2_kernel<<<NBLK, 256, 0, stream>>>(hs2, offs, csr, dinv, conv2_b,
                                          na3_w, na3_b, na4_w, na4_b, ggb, a1b,
                                          f1_w, f1_b, f2_w, f2_b, f3_w, f3_b,
                                          (float*)d_out, N);
}

// Round 11
// 301.502 us; speedup vs baseline: 3.2270x; 1.0958x over previous
//
#include <hip/hip_runtime.h>
#include <hip/hip_bf16.h>

typedef __hip_bfloat16 bf16;
typedef __attribute__((ext_vector_type(8))) short short8;
typedef __attribute__((ext_vector_type(4))) float f32x4;

__device__ __forceinline__ float tofb(bf16 v) { return __bfloat162float(v); }
__device__ __forceinline__ bf16 tob(float v) { return __float2bfloat16(v); }
// bf16x2 packed in a uint: low 16 bits = element 2m, high = element 2m+1
__device__ __forceinline__ float lo_f(unsigned v) { return __uint_as_float(v << 16); }
__device__ __forceinline__ float hi_f(unsigned v) { return __uint_as_float(v & 0xffff0000u); }
__device__ __forceinline__ unsigned f2bf_bits(float f) {  // RNE f32->bf16 bits
    unsigned u = __float_as_uint(f);
    return (u + 0x7fffu + ((u >> 16) & 1u)) >> 16;
}

#define CHUNK 4096   // edges per block in pack/bin

// fragment-buffer offsets (shorts): [t][s][lane][j] layout, 512 shorts per (t,s)
#define W2_OFF   0        // 128x128: t8 s4 -> 16384
#define NA1_OFF  16384    // 128x16:  t1 s4 -> 2048
#define NA3_OFF  18432    // 128x16:  t1 s4 -> 2048
#define F1_OFF   20480    // 48x64:   t4 s2 -> 4096 (k>=48 zero-padded)
#define F2_OFF   24576    // 64x32:   t2 s2 -> 2048
#define FRAG_TOT 26624

// ---------------- pass A: pack edges to (src<<16)|dst + 256-bucket histogram ----------------
__global__ __launch_bounds__(256) void pack_hist_kernel(const int* __restrict__ eidx,
                                                        unsigned* __restrict__ packed,
                                                        int* __restrict__ bhist, int E) {
    __shared__ int h[256];
    __shared__ int sodd;
    int t = threadIdx.x;
    h[t] = 0;
    if (t == 0) sodd = 0;
    __syncthreads();
    if (t < 32) atomicOr(&sodd, eidx[2 * t + 1]);
    __syncthreads();
    int stride = (sodd == 0) ? 2 : 1;
    int base = blockIdx.x * CHUNK;
#pragma unroll
    for (int k = 0; k < CHUNK / 256; ++k) {
        int e = base + k * 256 + t;
        if (e < E) {
            unsigned s = (unsigned)eidx[(size_t)e * stride];
            unsigned d = (unsigned)eidx[(size_t)E * stride + (size_t)e * stride];
            packed[e] = (s << 16) | d;
            atomicAdd(&h[d >> 8], 1);
        }
    }
    __syncthreads();
    if (h[t]) atomicAdd(&bhist[t], h[t]);
}

// ---------------- pass B: bucket scan (1 block) -> bases, cursors, offs[N]=E ----------------
__global__ __launch_bounds__(256) void bucket_scan_kernel(const int* __restrict__ bhist,
                                                          int* __restrict__ bbase,
                                                          int* __restrict__ bcur,
                                                          int* __restrict__ offs_n, int E) {
    __shared__ int s[256];
    int t = threadIdx.x;
    int my = bhist[t];
    s[t] = my;
    __syncthreads();
    for (int off = 1; off < 256; off <<= 1) {
        int v = (t >= off) ? s[t - off] : 0;
        __syncthreads();
        s[t] += v;
        __syncthreads();
    }
    int excl = s[t] - my;
    bbase[t] = excl;
    bcur[t] = excl;
    if (t == 0) offs_n[0] = E;
}

// ---------------- pass C: bin edges into bucket-contiguous regions ----------------
__global__ __launch_bounds__(256) void bin_kernel(const unsigned* __restrict__ packed,
                                                  int* __restrict__ bcur,
                                                  unsigned* __restrict__ binned, int E) {
    __shared__ int h[256];
    __shared__ int gbase[256];
    __shared__ int lcur[256];
    int t = threadIdx.x;
    h[t] = 0;
    lcur[t] = 0;
    __syncthreads();
    int base = blockIdx.x * CHUNK;
    unsigned v[CHUNK / 256];
#pragma unroll
    for (int k = 0; k < CHUNK / 256; ++k) {
        int e = base + k * 256 + t;
        v[k] = (e < E) ? packed[e] : 0u;
        if (e < E) atomicAdd(&h[(v[k] & 0xffffu) >> 8], 1);
    }
    __syncthreads();
    int mycnt = h[t];
    if (mycnt) gbase[t] = atomicAdd(&bcur[t], mycnt);
    __syncthreads();
#pragma unroll
    for (int k = 0; k < CHUNK / 256; ++k) {
        int e = base + k * 256 + t;
        if (e < E) {
            int b = (v[k] & 0xffffu) >> 8;
            int r = atomicAdd(&lcur[b], 1);
            binned[gbase[b] + r] = v[k];
        }
    }
}

// ---------------- pass D: per-bucket counting sort -> csr, offs, dinv ----------------
__global__ __launch_bounds__(256) void sort_kernel(const unsigned* __restrict__ binned,
                                                   const int* __restrict__ bbase,
                                                   const int* __restrict__ bhist,
                                                   int* __restrict__ offs,
                                                   float* __restrict__ dinv,
                                                   int* __restrict__ csr, int n) {
    __shared__ int lcnt[256];
    __shared__ int lcur[256];
    int b = blockIdx.x, t = threadIdx.x;
    int gstart = bbase[b];
    int bsize = bhist[b];
    lcnt[t] = 0;
    __syncthreads();
    for (int e = t; e < bsize; e += 256) {
        unsigned v = binned[gstart + e];
        atomicAdd(&lcnt[v & 255u], 1);
    }
    __syncthreads();
    int myc = lcnt[t];
    for (int off = 1; off < 256; off <<= 1) {
        int x = (t >= off) ? lcnt[t - off] : 0;
        __syncthreads();
        lcnt[t] += x;
        __syncthreads();
    }
    int excl = lcnt[t] - myc;
    int node = (b << 8) + t;
    if (node < n) {
        offs[node] = gstart + excl;
        dinv[node] = rsqrtf((float)myc + 1.0f);  // +1 self-loop
    }
    lcur[t] = excl;
    __syncthreads();
    for (int e = t; e < bsize; e += 256) {
        unsigned v = binned[gstart + e];
        int p = atomicAdd(&lcur[v & 255u], 1);
        csr[gstart + p] = (int)(v >> 16);
    }
}

// ---------------- pack ALL dense weights to MFMA B-fragment bf16 ----------------
// layout per weight (Kdim x Ndim): frag[(t*S + s)*512 + lane*8 + j] =
//   bf16(W[k][n]), k = s*32 + (lane>>4)*8 + j (0 if k>=Kdim), n = t*16 + (lane&15)
__global__ __launch_bounds__(256) void pack_frags_kernel(
    const float* __restrict__ w2, const float* __restrict__ na1w,
    const float* __restrict__ na3w, const float* __restrict__ f1w,
    const float* __restrict__ f2w, unsigned short* __restrict__ wf) {
    int idx = blockIdx.x * 256 + threadIdx.x;
    const float* src;
    int Kdim, Ndim, S, rel, off;
    if (idx < 16384)      { src = w2;   Kdim = 128; Ndim = 128; S = 4; rel = idx;          off = W2_OFF; }
    else if (idx < 18432) { src = na1w; Kdim = 128; Ndim = 16;  S = 4; rel = idx - 16384;  off = NA1_OFF; }
    else if (idx < 20480) { src = na3w; Kdim = 128; Ndim = 16;  S = 4; rel = idx - 18432;  off = NA3_OFF; }
    else if (idx < 24576) { src = f1w;  Kdim = 48;  Ndim = 64;  S = 2; rel = idx - 20480;  off = F1_OFF; }
    else if (idx < FRAG_TOT) { src = f2w; Kdim = 64; Ndim = 32; S = 2; rel = idx - 24576;  off = F2_OFF; }
    else return;
    int j = rel & 7;
    int lane = (rel >> 3) & 63;
    int s = (rel >> 9) % S;
    int t = rel / (512 * S);
    int k = s * 32 + ((lane >> 4) << 3) + j;
    int n = t * 16 + (lane & 15);
    unsigned short v = 0;
    if (k < Kdim) v = (unsigned short)f2bf_bits(src[k * Ndim + n]);
    wf[off + rel] = v;
}

// ---------------- pre-pass (16 nodes/block): hs1 = dinv*(x@W1); gg branch (bf16 out) ------

__global__ __launch_bounds__(256) void pre_kernel(
    const float* __restrict__ x, const float* __restrict__ conv1_w,
    const float* __restrict__ ln1_w, const float* __restrict__ ln1_b,
    const float* __restrict__ ln2_w, const float* __restrict__ ln2_b,
    const float* __restrict__ dinv,
    bf16* __restrict__ hs1, bf16* __restrict__ gg, int n) {
    int tid = threadIdx.x;
    int i0 = blockIdx.x * 16;
    __shared__ float xls[16 * 20];   // [node][16] pad 20
    __shared__ float tg[16 * 36];    // ln1 out [node][32] pad 36
    {
        int nn = tid >> 4, cc = tid & 15;
        int i = i0 + nn;
        xls[nn * 20 + cc] = (i < n) ? x[(size_t)i * 16 + cc] : 0.f;
    }
    __syncthreads();
    {
        int c = tid & 127, half = tid >> 7;
        float h[8];
#pragma unroll
        for (int r = 0; r < 8; ++r) h[r] = 0.f;
#pragma unroll
        for (int k = 0; k < 16; ++k) {
            float w = conv1_w[k * 128 + c];
#pragma unroll
            for (int r = 0; r < 8; ++r) h[r] += xls[(half + 2 * r) * 20 + k] * w;
        }
#pragma unroll
        for (int r = 0; r < 8; ++r) {
            int i = i0 + half + 2 * r;
            if (i < n) hs1[(size_t)i * 128 + c] = tob(dinv[i] * h[r]);
        }
    }
    {
        int c = tid & 31, q = tid >> 5;
        float t0 = ln1_b[c], t1 = t0;
#pragma unroll
        for (int k = 0; k < 16; ++k) {
            float w = ln1_w[k * 32 + c];
            t0 += xls[q * 20 + k] * w;
            t1 += xls[(q + 8) * 20 + k] * w;
        }
        tg[q * 36 + c] = fmaxf(t0, 0.f);
        tg[(q + 8) * 36 + c] = fmaxf(t1, 0.f);
    }
    __syncthreads();
    {
        int nn = tid >> 4, cc = tid & 15;
        float t = ln2_b[cc];
#pragma unroll 8
        for (int k = 0; k < 32; ++k) t += tg[nn * 36 + k] * ln2_w[k * 16 + cc];
        int i = i0 + nn;
        if (i < n) gg[(size_t)i * 16 + cc] = tob(fmaxf(t, 0.f));
    }
}

// gather (16 nodes/block): group g (16 lanes) owns node i0+g. Lane sl covers cols sl*8..+7.
#define ACC8(v)                              \
    a0 += lo_f((v).x); a1 += hi_f((v).x);    \
    a2 += lo_f((v).y); a3 += hi_f((v).y);    \
    a4 += lo_f((v).z); a5 += hi_f((v).z);    \
    a6 += lo_f((v).w); a7 += hi_f((v).w);

#define GATHER16(hs, ...)                                                            \
    {                                                                                \
        const char* base = (const char*)(hs);                                        \
        int off16 = sl * 16;                                                         \
        float a0 = 0.f, a1 = 0.f, a2 = 0.f, a3 = 0.f,                                \
              a4 = 0.f, a5 = 0.f, a6 = 0.f, a7 = 0.f;                                \
        int e0 = 0, e1 = 0;                                                          \
        if (valid) { e0 = offs[i]; e1 = offs[i + 1]; }                               \
        if (valid) { uint4 v = *(const uint4*)(base + (size_t)i * 256 + off16); ACC8(v) } \
        for (int cb = e0; cb < e1; cb += 16) {                                       \
            int idxv = (cb + sl < e1) ? csr[cb + sl] : 0;                            \
            _Pragma("unroll")                                                        \
            for (int u = 0; u < 4; ++u) {                                            \
                int e = cb + u * 4;                                                  \
                if (e >= e1) break;                                                  \
                int s0 = __shfl(idxv, glane + u * 4 + 0);                            \
                int s1 = __shfl(idxv, glane + u * 4 + 1);                            \
                int s2 = __shfl(idxv, glane + u * 4 + 2);                            \
                int s3 = __shfl(idxv, glane + u * 4 + 3);                            \
                bool m1 = (e + 1 < e1), m2 = (e + 2 < e1), m3 = (e + 3 < e1);        \
                int j1 = m1 ? s1 : i, j2 = m2 ? s2 : i, j3 = m3 ? s3 : i;            \
                uint4 v0 = *(const uint4*)(base + (size_t)s0 * 256 + off16);         \
                uint4 v1 = *(const uint4*)(base + (size_t)j1 * 256 + off16);         \
                uint4 v2 = *(const uint4*)(base + (size_t)j2 * 256 + off16);         \
                uint4 v3 = *(const uint4*)(base + (size_t)j3 * 256 + off16);         \
                ACC8(v0)                                                             \
                if (m1) { ACC8(v1) }                                                 \
                if (m2) { ACC8(v2) }                                                 \
                if (m3) { ACC8(v3) }                                                 \
            }                                                                        \
        }                                                                            \
        __VA_ARGS__                                                                  \
    }

// epilogue: relu(dinv*acc + bias) -> bf16 row in xsb (stride 272 B)
#define STORE_X_BF16(biasptr)                                                        \
    {                                                                                \
        float r0 = 0.f; float r1 = 0.f; float r2 = 0.f; float r3 = 0.f;              \
        float r4 = 0.f; float r5 = 0.f; float r6 = 0.f; float r7 = 0.f;              \
        if (valid) {                                                                 \
            float di = dinv[i];                                                      \
            const float* b = (biasptr) + sl * 8;                                     \
            r0 = fmaxf(di * a0 + b[0], 0.f); r1 = fmaxf(di * a1 + b[1], 0.f);        \
            r2 = fmaxf(di * a2 + b[2], 0.f); r3 = fmaxf(di * a3 + b[3], 0.f);        \
            r4 = fmaxf(di * a4 + b[4], 0.f); r5 = fmaxf(di * a5 + b[5], 0.f);        \
            r6 = fmaxf(di * a6 + b[6], 0.f); r7 = fmaxf(di * a7 + b[7], 0.f);        \
        }                                                                            \
        uint4 pk;                                                                    \
        pk.x = f2bf_bits(r0) | (f2bf_bits(r1) << 16);                                \
        pk.y = f2bf_bits(r2) | (f2bf_bits(r3) << 16);                                \
        pk.z = f2bf_bits(r4) | (f2bf_bits(r5) << 16);                                \
        pk.w = f2bf_bits(r6) | (f2bf_bits(r7) << 16);                                \
        *(uint4*)((char*)xsb + g * 272 + sl * 16) = pk;                              \
    }

// ---------------- agg1: x1=relu(agg+b1); hs2=dinv*(x1@W2) MFMA; a1 branch MFMA ----------------

__global__ __launch_bounds__(256) void agg1_kernel(
    const bf16* __restrict__ hs1, const int* __restrict__ offs, const int* __restrict__ csr,
    const float* __restrict__ dinv, const float* __restrict__ conv1_b,
    const unsigned short* __restrict__ wfrag,
    const float* __restrict__ na1_b,
    const float* __restrict__ na2_w, const float* __restrict__ na2_b,
    bf16* __restrict__ hs2, bf16* __restrict__ a1, int n) {
    int tid = threadIdx.x;
    int g = tid >> 4, sl = tid & 15;
    int glane = tid & 48;
    int i0 = blockIdx.x * 16;
    int i = i0 + g;
    bool valid = (i < n);
    __shared__ short xsb[16 * 136];   // x1 bf16, row stride 272 B
    __shared__ float pna[4 * 256];    // na1 per-wave partials
    __shared__ float t1s[16 * 20];
    GATHER16(hs1, STORE_X_BF16(conv1_b))
    __syncthreads();
    int lane = tid & 63, wv = tid >> 6, quad = lane >> 4, lm = lane & 15;
    // conv2 via MFMA: wave wv covers col-tiles 2wv, 2wv+1
    {
        int t0 = wv * 2;
        f32x4 acc0 = {0.f, 0.f, 0.f, 0.f};
        f32x4 acc1 = {0.f, 0.f, 0.f, 0.f};
#pragma unroll
        for (int s = 0; s < 4; ++s) {
            short8 a = *(const short8*)((const char*)xsb + lm * 272 + s * 64 + quad * 16);
            short8 b0 = *(const short8*)(wfrag + W2_OFF + ((t0 * 4 + s) * 64 + lane) * 8);
            short8 b1 = *(const short8*)(wfrag + W2_OFF + (((t0 + 1) * 4 + s) * 64 + lane) * 8);
            acc0 = __builtin_amdgcn_mfma_f32_16x16x32_bf16(a, b0, acc0, 0, 0, 0);
            acc1 = __builtin_amdgcn_mfma_f32_16x16x32_bf16(a, b1, acc1, 0, 0, 0);
        }
#pragma unroll
        for (int r = 0; r < 4; ++r) {
            int iN = i0 + quad * 4 + r;
            if (iN < n) {
                float di = dinv[iN];
                hs2[(size_t)iN * 128 + t0 * 16 + lm] = tob(di * acc0[r]);
                hs2[(size_t)iN * 128 + (t0 + 1) * 16 + lm] = tob(di * acc1[r]);
            }
        }
    }
    // na1 via MFMA: wave wv computes K-step s=wv partial
    {
        f32x4 acc = {0.f, 0.f, 0.f, 0.f};
        short8 a = *(const short8*)((const char*)xsb + lm * 272 + wv * 64 + quad * 16);
        short8 b = *(const short8*)(wfrag + NA1_OFF + (wv * 64 + lane) * 8);
        acc = __builtin_amdgcn_mfma_f32_16x16x32_bf16(a, b, acc, 0, 0, 0);
#pragma unroll
        for (int r = 0; r < 4; ++r) pna[wv * 256 + (quad * 4 + r) * 16 + lm] = acc[r];
    }
    __syncthreads();
    int nn = tid >> 4, cc = tid & 15;
    {
        float t = na1_b[cc] + pna[nn * 16 + cc] + pna[256 + nn * 16 + cc]
                + pna[512 + nn * 16 + cc] + pna[768 + nn * 16 + cc];
        t1s[nn * 20 + cc] = fmaxf(t, 0.f);
    }
    __syncthreads();
    {
        float t2 = na2_b[cc];
#pragma unroll
        for (int k = 0; k < 16; ++k) t2 += t1s[nn * 20 + k] * na2_w[k * 16 + cc];
        int iN = i0 + nn;
        if (iN < n) a1[(size_t)iN * 16 + cc] = tob(fmaxf(t2, 0.f));
    }
}

// ---------------- agg2: x2=relu(agg+b2); a2 MFMA; head f1/f2 MFMA, f3 -> sigmoid ----------------

__global__ __launch_bounds__(256) void agg2_kernel(
    const bf16* __restrict__ hs2, const int* __restrict__ offs, const int* __restrict__ csr,
    const float* __restrict__ dinv, const float* __restrict__ conv2_b,
    const unsigned short* __restrict__ wfrag,
    const float* __restrict__ na3_b,
    const float* __restrict__ na4_w, const float* __restrict__ na4_b,
    const bf16* __restrict__ gg, const bf16* __restrict__ a1,
    const float* __restrict__ f1_b, const float* __restrict__ f2_b,
    const float* __restrict__ f3_w, const float* __restrict__ f3_b,
    float* __restrict__ out, int n) {
    int tid = threadIdx.x;
    int g = tid >> 4, sl = tid & 15;
    int glane = tid & 48;
    int i0 = blockIdx.x * 16;
    int i = i0 + g;
    bool valid = (i < n);
    __shared__ short xsb[16 * 136];   // x2 bf16, stride 272 B
    __shared__ float pna[4 * 256];
    __shared__ float t1s[16 * 20];
    __shared__ short xf[16 * 72];     // concat [gg|a1|a2|0] bf16, stride 144 B
    __shared__ short y1[16 * 72];     // f1 out bf16, stride 144 B
    __shared__ float y2[16 * 36];     // f2 out f32
    GATHER16(hs2, STORE_X_BF16(conv2_b))
    __syncthreads();
    int lane = tid & 63, wv = tid >> 6, quad = lane >> 4, lm = lane & 15;
    // na3 via MFMA: wave wv K-step s=wv partial
    {
        f32x4 acc = {0.f, 0.f, 0.f, 0.f};
        short8 a = *(const short8*)((const char*)xsb + lm * 272 + wv * 64 + quad * 16);
        short8 b = *(const short8*)(wfrag + NA3_OFF + (wv * 64 + lane) * 8);
        acc = __builtin_amdgcn_mfma_f32_16x16x32_bf16(a, b, acc, 0, 0, 0);
#pragma unroll
        for (int r = 0; r < 4; ++r) pna[wv * 256 + (quad * 4 + r) * 16 + lm] = acc[r];
    }
    __syncthreads();
    int nn = tid >> 4, cc = tid & 15;
    int iN = i0 + nn;
    {
        float t = na3_b[cc] + pna[nn * 16 + cc] + pna[256 + nn * 16 + cc]
                + pna[512 + nn * 16 + cc] + pna[768 + nn * 16 + cc];
        t1s[nn * 20 + cc] = fmaxf(t, 0.f);
        bool v = (iN < n);
        size_t ib = (size_t)iN * 16 + cc;
        xf[nn * 72 + cc]      = v ? (short)((const unsigned short*)gg)[ib] : (short)0;
        xf[nn * 72 + 16 + cc] = v ? (short)((const unsigned short*)a1)[ib] : (short)0;
        xf[nn * 72 + 48 + cc] = 0;   // K-pad
    }
    __syncthreads();
    {
        float t2 = na4_b[cc];
#pragma unroll
        for (int k = 0; k < 16; ++k) t2 += t1s[nn * 20 + k] * na4_w[k * 16 + cc];
        xf[nn * 72 + 32 + cc] = (short)f2bf_bits(fmaxf(t2, 0.f));
    }
    __syncthreads();
    // f1 via MFMA: wave wv -> col-tile wv (64 cols / 4)
    {
        f32x4 acc = {0.f, 0.f, 0.f, 0.f};
#pragma unroll
        for (int s = 0; s < 2; ++s) {
            short8 a = *(const short8*)((const char*)xf + lm * 144 + s * 64 + quad * 16);
            short8 b = *(const short8*)(wfrag + F1_OFF + ((wv * 2 + s) * 64 + lane) * 8);
            acc = __builtin_amdgcn_mfma_f32_16x16x32_bf16(a, b, acc, 0, 0, 0);
        }
        float bia = f1_b[wv * 16 + lm];
#pragma unroll
        for (int r = 0; r < 4; ++r)
            y1[(quad * 4 + r) * 72 + wv * 16 + lm] = (short)f2bf_bits(fmaxf(acc[r] + bia, 0.f));
    }
    __syncthreads();
    // f2 via MFMA: waves 0,1 -> col-tiles 0,1 (32 cols)
    if (wv < 2) {
        f32x4 acc = {0.f, 0.f, 0.f, 0.f};
#pragma unroll
        for (int s = 0; s < 2; ++s) {
            short8 a = *(const short8*)((const char*)y1 + lm * 144 + s * 64 + quad * 16);
            short8 b = *(const short8*)(wfrag + F2_OFF + ((wv * 2 + s) * 64 + lane) * 8);
            acc = __builtin_amdgcn_mfma_f32_16x16x32_bf16(a, b, acc, 0, 0, 0);
        }
        float bia = f2_b[wv * 16 + lm];
#pragma unroll
        for (int r = 0; r < 4; ++r)
            y2[(quad * 4 + r) * 36 + wv * 16 + lm] = fmaxf(acc[r] + bia, 0.f);
    }
    __syncthreads();
    if (tid < 16) {
        float z = f3_b[0];
#pragma unroll
        for (int k = 0; k < 32; ++k) z += y2[tid * 36 + k] * f3_w[k];
        int io = i0 + tid;
        if (io < n) out[io] = 1.f / (1.f + expf(-z));
    }
}

// ---------------- launch ----------------

extern "C" void kernel_launch(void* const* d_in, const int* in_sizes, int n_in,
                              void* d_out, int out_size, void* d_ws, size_t ws_size,
                              hipStream_t stream) {
    const float* x       = (const float*)d_in[0];
    const int*   eidx    = (const int*)d_in[1];
    const float* conv1_w = (const float*)d_in[2];
    const float* conv1_b = (const float*)d_in[3];
    const float* conv2_w = (const float*)d_in[4];
    const float* conv2_b = (const float*)d_in[5];
    const float* ln1_w   = (const float*)d_in[6];
    const float* ln1_b   = (const float*)d_in[7];
    const float* ln2_w   = (const float*)d_in[8];
    const float* ln2_b   = (const float*)d_in[9];
    const float* na1_w   = (const float*)d_in[10];
    const float* na1_b   = (const float*)d_in[11];
    const float* na2_w   = (const float*)d_in[12];
    const float* na2_b   = (const float*)d_in[13];
    const float* na3_w   = (const float*)d_in[14];
    const float* na3_b   = (const float*)d_in[15];
    const float* na4_w   = (const float*)d_in[16];
    const float* na4_b   = (const float*)d_in[17];
    const float* f1_w    = (const float*)d_in[18];
    const float* f1_b    = (const float*)d_in[19];
    const float* f2_w    = (const float*)d_in[20];
    const float* f2_b    = (const float*)d_in[21];
    const float* f3_w    = (const float*)d_in[22];
    const float* f3_b    = (const float*)d_in[23];

    const int N = in_sizes[0] / 16;          // 50000 (< 65536: 16-bit packing valid)
    const int E = in_sizes[1] / 2;
    const int NBUCK = (N + 255) >> 8;
    const int EB = (E + CHUNK - 1) / CHUNK;
    const int NBLK = (N + 15) / 16;

    // workspace carve-up (256B aligned)
    char* p = (char*)d_ws;
    auto alloc = [&](size_t bytes) {
        char* r = p;
        p += (bytes + 255) & ~(size_t)255;
        return r;
    };
    int*            bhist  = (int*)alloc(256 * 4);
    int*            bbase  = (int*)alloc(256 * 4);
    int*            bcur   = (int*)alloc(256 * 4);
    int*            offs   = (int*)alloc(((size_t)N + 1) * 4);
    unsigned*       packed = (unsigned*)alloc((size_t)E * 4);   // later reused as csr
    unsigned*       binned = (unsigned*)alloc((size_t)E * 4);
    float*          dinv   = (float*)alloc((size_t)N * 4);
    unsigned short* wfrag  = (unsigned short*)alloc((size_t)FRAG_TOT * 2);
    bf16*           hs1    = (bf16*)alloc((size_t)N * 128 * 2);
    bf16*           hs2    = (bf16*)alloc((size_t)N * 128 * 2);
    bf16*           ggb    = (bf16*)alloc((size_t)N * 16 * 2);
    bf16*           a1b    = (bf16*)alloc((size_t)N * 16 * 2);
    int*            csr    = (int*)packed;  // alias: packed dead after bin_kernel

    hipMemsetAsync(bhist, 0, 256 * 4, stream);
    pack_hist_kernel<<<EB, 256, 0, stream>>>(eidx, packed, bhist, E);
    bucket_scan_kernel<<<1, 256, 0, stream>>>(bhist, bbase, bcur, offs + N, E);
    bin_kernel<<<EB, 256, 0, stream>>>(packed, bcur, binned, E);
    sort_kernel<<<NBUCK, 256, 0, stream>>>(binned, bbase, bhist, offs, dinv, csr, N);

    pack_frags_kernel<<<(FRAG_TOT + 255) / 256, 256, 0, stream>>>(conv2_w, na1_w, na3_w, f1_w, f2_w, wfrag);
    pre_kernel<<<NBLK, 256, 0, stream>>>(x, conv1_w, ln1_w, ln1_b, ln2_w, ln2_b, dinv, hs1, ggb, N);
    agg1_kernel<<<NBLK, 256, 0, stream>>>(hs1, offs, csr, dinv, conv1_b, wfrag,
                                          na1_b, na2_w, na2_b, hs2, a1b, N);
    agg2_kernel<<<NBLK, 256, 0, stream>>>(hs2, offs, csr, dinv, conv2_b, wfrag,
                                          na3_b, na4_w, na4_b, ggb, a1b,
                                          f1_b, f2_b, f3_w, f3_b,
                                          (float*)d_out, N);
}